// Round 8
// baseline (1129.240 us; speedup 1.0000x reference)
//
#include <hip/hip_runtime.h>

#define S 2048
#define HID 1024
#define HK 4
#define HV 8
#define DK 128
#define DV 128
#define KEY_DIM 512
#define VAL_DIM 1024
#define CONV_DIM 2048
#define QKVZ_N 3072
#define NEXP 8
#define INTER 512
#define EPS 1e-6f
#define CK 64
#define NC 32

typedef unsigned short u16;
typedef unsigned int u32;
typedef __attribute__((ext_vector_type(8))) short bf16x8;
typedef __attribute__((ext_vector_type(4))) float f32x4;

__device__ __forceinline__ u16 f2b(float f) {
  u32 u = __builtin_bit_cast(u32, f);
  u += 0x7fff + ((u >> 16) & 1);
  return (u16)(u >> 16);
}

__device__ __forceinline__ void gload16(const u16* g, u16* l) {
  __builtin_amdgcn_global_load_lds(
      (const __attribute__((address_space(1))) void*)g,
      (__attribute__((address_space(3))) void*)l, 16, 0, 0);
}

// ---------------- zero-centered RMSNorm -> f32 out + bf16 out
__global__ __launch_bounds__(256) void k_rms(const float* __restrict__ x,
                                             const float* __restrict__ w,
                                             float* __restrict__ out,
                                             u16* __restrict__ outb) {
  const int row = blockIdx.x;
  const int tid = threadIdx.x;
  const float* xr = x + (size_t)row * HID;
  float4 v = ((const float4*)xr)[tid];
  float ss = v.x*v.x + v.y*v.y + v.z*v.z + v.w*v.w;
  for (int m = 1; m < 64; m <<= 1) ss += __shfl_xor(ss, m);
  __shared__ float sred[4];
  if ((tid & 63) == 0) sred[tid >> 6] = ss;
  __syncthreads();
  float tot = sred[0] + sred[1] + sred[2] + sred[3];
  float scale = 1.0f / sqrtf(tot * (1.0f / HID) + EPS);
  float4 wv = ((const float4*)w)[tid];
  float4 o;
  o.x = v.x * scale * (1.0f + wv.x);
  o.y = v.y * scale * (1.0f + wv.y);
  o.z = v.z * scale * (1.0f + wv.z);
  o.w = v.w * scale * (1.0f + wv.w);
  ((float4*)(out + (size_t)row * HID))[tid] = o;
  u32 p0 = (u32)f2b(o.x) | ((u32)f2b(o.y) << 16);
  u32 p1 = (u32)f2b(o.z) | ((u32)f2b(o.w) << 16);
  *(uint2*)&outb[(size_t)row * HID + tid * 4] = make_uint2(p0, p1);
}

// ---------------- transpose+cast: src f32 [K][N] -> dst bf16 [N][K], batched z
__global__ __launch_bounds__(256) void k_transp(const float* __restrict__ src,
                                                u16* __restrict__ dst,
                                                int K, int N) {
  __shared__ float t[32][33];
  const size_t bo = (size_t)blockIdx.z * K * N;
  src += bo; dst += bo;
  int n0 = blockIdx.x * 32, k0 = blockIdx.y * 32;
  int tx = threadIdx.x & 31, ty = threadIdx.x >> 5;
#pragma unroll
  for (int i = 0; i < 32; i += 8)
    t[ty + i][tx] = src[(size_t)(k0 + ty + i) * N + n0 + tx];
  __syncthreads();
#pragma unroll
  for (int i = 0; i < 32; i += 8)
    dst[(size_t)(n0 + ty + i) * K + k0 + tx] = f2b(t[tx][ty + i]);
}

// ---------------- f32 GEMM 128x128 tile, 8x8/thread, reg-double-buffered
__global__ __launch_bounds__(256) void k_sgemm2(const float* __restrict__ A,
                                                const float* __restrict__ B,
                                                const float* __restrict__ Cadd,
                                                float* __restrict__ C,
                                                int M, int N, int K) {
  __shared__ float As[16][132];
  __shared__ float Bs[16][132];
  const int tid = threadIdx.x;
  const int ty = tid >> 4, tx = tid & 15;
  const int m0 = blockIdx.y * 128, n0 = blockIdx.x * 128;
  const int ar = tid >> 1, ak = (tid & 1) * 8;
  const int br = tid >> 4, bc = (tid & 15) * 8;
  float acc[8][8] = {};
  float4 ra0, ra1, rb0, rb1;
  ra0 = *(const float4*)&A[(size_t)(m0 + ar) * K + ak];
  ra1 = *(const float4*)&A[(size_t)(m0 + ar) * K + ak + 4];
  rb0 = *(const float4*)&B[(size_t)br * N + n0 + bc];
  rb1 = *(const float4*)&B[(size_t)br * N + n0 + bc + 4];
  for (int k0 = 0; k0 < K; k0 += 16) {
    As[ak + 0][ar] = ra0.x; As[ak + 1][ar] = ra0.y;
    As[ak + 2][ar] = ra0.z; As[ak + 3][ar] = ra0.w;
    As[ak + 4][ar] = ra1.x; As[ak + 5][ar] = ra1.y;
    As[ak + 6][ar] = ra1.z; As[ak + 7][ar] = ra1.w;
    *(float4*)&Bs[br][bc]     = rb0;
    *(float4*)&Bs[br][bc + 4] = rb1;
    __syncthreads();
    if (k0 + 16 < K) {
      ra0 = *(const float4*)&A[(size_t)(m0 + ar) * K + k0 + 16 + ak];
      ra1 = *(const float4*)&A[(size_t)(m0 + ar) * K + k0 + 16 + ak + 4];
      rb0 = *(const float4*)&B[(size_t)(k0 + 16 + br) * N + n0 + bc];
      rb1 = *(const float4*)&B[(size_t)(k0 + 16 + br) * N + n0 + bc + 4];
    }
#pragma unroll
    for (int kk = 0; kk < 16; ++kk) {
      float4 aA = *(const float4*)&As[kk][ty * 8];
      float4 aB = *(const float4*)&As[kk][ty * 8 + 4];
      float4 bA = *(const float4*)&Bs[kk][tx * 8];
      float4 bB = *(const float4*)&Bs[kk][tx * 8 + 4];
      float a[8] = {aA.x, aA.y, aA.z, aA.w, aB.x, aB.y, aB.z, aB.w};
      float b[8] = {bA.x, bA.y, bA.z, bA.w, bB.x, bB.y, bB.z, bB.w};
#pragma unroll
      for (int i = 0; i < 8; ++i)
#pragma unroll
        for (int j = 0; j < 8; ++j) acc[i][j] += a[i] * b[j];
    }
    __syncthreads();
  }
#pragma unroll
  for (int i = 0; i < 8; ++i) {
    size_t off = (size_t)(m0 + ty * 8 + i) * N + n0 + tx * 8;
    float4 o0 = {acc[i][0], acc[i][1], acc[i][2], acc[i][3]};
    float4 o1 = {acc[i][4], acc[i][5], acc[i][6], acc[i][7]};
    if (Cadd) {
      float4 c0 = *(const float4*)&Cadd[off];
      float4 c1 = *(const float4*)&Cadd[off + 4];
      o0.x += c0.x; o0.y += c0.y; o0.z += c0.z; o0.w += c0.w;
      o1.x += c1.x; o1.y += c1.y; o1.z += c1.z; o1.w += c1.w;
    }
    *(float4*)&C[off] = o0;
    *(float4*)&C[off + 4] = o1;
  }
}

// ---------------- ba = x1 @ W_ba  (N=16)
__global__ __launch_bounds__(256) void k_ba(const float* __restrict__ x1,
                                            const float* __restrict__ Wba,
                                            float* __restrict__ ba) {
  const int t = blockIdx.x, tid = threadIdx.x;
  const int n = tid >> 4, kl = tid & 15;
  const float* xr = x1 + (size_t)t * HID;
  float s = 0.f;
  for (int k = kl; k < HID; k += 16) s += xr[k] * Wba[k * 16 + n];
  for (int m = 1; m < 16; m <<= 1) s += __shfl_xor(s, m);
  if (kl == 0) ba[t * 16 + n] = s;
}

// ---------------- beta = sigmoid(b); g = -exp(A_log)*softplus(a+dt_bias)
__global__ __launch_bounds__(256) void k_bg(const float* __restrict__ ba,
                                            const float* __restrict__ dt_bias,
                                            const float* __restrict__ A_log,
                                            float* __restrict__ gb,
                                            float* __restrict__ beta) {
  int i = blockIdx.x * 256 + threadIdx.x;
  if (i >= S * HV) return;
  int t = i >> 3, h = i & 7;
  float b = ba[t * 16 + h];
  float a = ba[t * 16 + 8 + h];
  beta[i] = 1.f / (1.f + expf(-b));
  float x = a + dt_bias[h];
  float sp = fmaxf(x, 0.f) + log1pf(expf(-fabsf(x)));
  gb[i] = -expf(A_log[h]) * sp;
}

// ---------------- causal depthwise conv (K=4) + silu on qkvz cols [0,2048)
__global__ __launch_bounds__(256) void k_conv(const float* __restrict__ qkvz,
                                              const float* __restrict__ cw,
                                              float* __restrict__ conv) {
  int idx = blockIdx.x * 256 + threadIdx.x;
  int t = idx >> 11, c = idx & 2047;
  float4 w = ((const float4*)cw)[c];
  float acc = 0.f;
  if (t >= 3) {
    acc = qkvz[(size_t)(t - 3) * QKVZ_N + c] * w.x
        + qkvz[(size_t)(t - 2) * QKVZ_N + c] * w.y
        + qkvz[(size_t)(t - 1) * QKVZ_N + c] * w.z
        + qkvz[(size_t)(t    ) * QKVZ_N + c] * w.w;
  } else {
    if (t - 3 >= 0) acc += qkvz[(size_t)(t - 3) * QKVZ_N + c] * w.x;
    if (t - 2 >= 0) acc += qkvz[(size_t)(t - 2) * QKVZ_N + c] * w.y;
    if (t - 1 >= 0) acc += qkvz[(size_t)(t - 1) * QKVZ_N + c] * w.z;
    acc += qkvz[(size_t)t * QKVZ_N + c] * w.w;
  }
  conv[idx] = acc / (1.f + expf(-acc));
}

// ---------------- l2-normalize q,k per source head; repeat to 8 dest heads
__global__ __launch_bounds__(512) void k_prep(const float* __restrict__ conv,
                                              float* __restrict__ qn,
                                              float* __restrict__ kn) {
  const int t = blockIdx.x, tid = threadIdx.x;
  const int sh = tid >> 7;
  const int d = tid & 127;
  float qv = conv[(size_t)t * CONV_DIM + sh * DK + d];
  float kv = conv[(size_t)t * CONV_DIM + KEY_DIM + sh * DK + d];
  float sq = qv * qv, sk = kv * kv;
  for (int m = 1; m < 64; m <<= 1) { sq += __shfl_xor(sq, m); sk += __shfl_xor(sk, m); }
  __shared__ float rq[8], rk[8];
  const int wave = tid >> 6;
  if ((tid & 63) == 0) { rq[wave] = sq; rk[wave] = sk; }
  __syncthreads();
  float sumq = rq[sh * 2] + rq[sh * 2 + 1];
  float sumk = rk[sh * 2] + rk[sh * 2 + 1];
  float qs = (1.f / sqrtf(sumq + EPS)) * 0.08838834764831845f;
  float ks = 1.f / sqrtf(sumk + EPS);
  float qo = qv * qs, ko = kv * ks;
  size_t b0 = (size_t)t * 1024 + (size_t)(sh * 2) * DK + d;
  qn[b0] = qo; qn[b0 + DK] = qo;
  kn[b0] = ko; kn[b0 + DK] = ko;
}

// ================= chunked gated delta rule =================
__global__ __launch_bounds__(256) void k_chunkA(
    const float* __restrict__ qn, const float* __restrict__ kn,
    const float* __restrict__ conv, const float* __restrict__ gbuf,
    const float* __restrict__ betab,
    float* __restrict__ Upre, float* __restrict__ WpT,
    float* __restrict__ Qdt, float* __restrict__ Kdm,
    float* __restrict__ BqT, float* __restrict__ dec) {
  const int h = blockIdx.x >> 5;
  const int ch = blockIdx.x & 31;
  const int tid = threadIdx.x;
  const int t_base = ch * CK;

  __shared__ float KT[128][68];
  __shared__ float UB[8704];
  __shared__ float Am[64][68];
  __shared__ float Mm[64][68];
  __shared__ float c_l[64], b_l[64], sW[64], seQ[64], sKd[64];

#pragma unroll
  for (int i = 0; i < 8; ++i) {
    int w = (i * 256 + tid) * 4;
    int tt = w >> 7, r = w & 127;
    float4 v = *(const float4*)&kn[(size_t)(t_base + tt) * 1024 + h * 128 + r];
    KT[r + 0][tt] = v.x; KT[r + 1][tt] = v.y; KT[r + 2][tt] = v.z; KT[r + 3][tt] = v.w;
  }
  if (tid < 64) {
    c_l[tid] = gbuf[(t_base + tid) * HV + h];
    b_l[tid] = betab[(t_base + tid) * HV + h];
  }
  __syncthreads();
  if (tid == 0) {
    float run = 0.f;
    for (int t = 0; t < 64; ++t) { run += c_l[t]; c_l[t] = run; }
    dec[h * NC + ch] = expf(run);
  }
  __syncthreads();
  if (tid < 64) {
    sW[tid] = b_l[tid] * expf(c_l[tid]);
    seQ[tid] = expf(c_l[tid]);
    sKd[tid] = expf(c_l[63] - c_l[tid]);
  }
  __syncthreads();

  {
    const int t0 = (tid >> 4) * 4, j0 = (tid & 15) * 4;
    float acc[4][4] = {};
    for (int r = 0; r < 128; ++r) {
      float4 a = *(const float4*)&KT[r][t0];
      float4 b = *(const float4*)&KT[r][j0];
      float av[4] = {a.x, a.y, a.z, a.w};
      float bv[4] = {b.x, b.y, b.z, b.w};
#pragma unroll
      for (int i = 0; i < 4; ++i)
#pragma unroll
        for (int j = 0; j < 4; ++j) acc[i][j] += av[i] * bv[j];
    }
#pragma unroll
    for (int i = 0; i < 4; ++i)
#pragma unroll
      for (int j = 0; j < 4; ++j) {
        int t = t0 + i, jj = j0 + j;
        Am[t][jj] = (jj < t) ? b_l[t] * expf(c_l[t] - c_l[jj]) * acc[i][j] : 0.f;
      }
  }
  __syncthreads();

  if (tid < 64) {
    const int c = tid;
    Mm[0][c] = (c == 0) ? 1.f : 0.f;
    for (int t = 1; t < 64; ++t) {
      float a = (c == t) ? 1.f : 0.f;
      for (int j = 0; j < t; ++j) a -= Am[t][j] * Mm[j][c];
      Mm[t][c] = a;
    }
  }
  __syncthreads();

  float* Vsm = UB;
#pragma unroll
  for (int i = 0; i < 8; ++i) {
    int w = (i * 256 + tid) * 4;
    int j = w >> 7, cc = w & 127;
    float4 v = *(const float4*)&conv[(size_t)(t_base + j) * CONV_DIM + 1024 + h * 128 + cc];
    float bj = b_l[j];
    v.x *= bj; v.y *= bj; v.z *= bj; v.w *= bj;
    *(float4*)&Vsm[j * 132 + cc] = v;
  }
  __syncthreads();

  const size_t cb = (size_t)h * NC + ch;
  {
    const int t0 = (tid >> 4) * 4, c0 = (tid & 15) * 8;
    float acc[4][8] = {};
    for (int j = 0; j < 64; ++j) {
      float m[4];
#pragma unroll
      for (int i = 0; i < 4; ++i) m[i] = Mm[t0 + i][j];
      float4 va = *(const float4*)&Vsm[j * 132 + c0];
      float4 vb = *(const float4*)&Vsm[j * 132 + c0 + 4];
      float v[8] = {va.x, va.y, va.z, va.w, vb.x, vb.y, vb.z, vb.w};
#pragma unroll
      for (int i = 0; i < 4; ++i)
#pragma unroll
        for (int c = 0; c < 8; ++c) acc[i][c] += m[i] * v[c];
    }
#pragma unroll
    for (int i = 0; i < 4; ++i) {
      float4 o0 = {acc[i][0], acc[i][1], acc[i][2], acc[i][3]};
      float4 o1 = {acc[i][4], acc[i][5], acc[i][6], acc[i][7]};
      *(float4*)&Upre[cb * 8192 + (size_t)(t0 + i) * 128 + c0] = o0;
      *(float4*)&Upre[cb * 8192 + (size_t)(t0 + i) * 128 + c0 + 4] = o1;
    }
  }
  {
    const int r0 = (tid >> 3) * 4, t0 = (tid & 7) * 8;
    float acc[4][8] = {};
    for (int j = 0; j < 64; ++j) {
      float s = sW[j];
      float kk[4];
#pragma unroll
      for (int i = 0; i < 4; ++i) kk[i] = KT[r0 + i][j] * s;
      float m[8];
#pragma unroll
      for (int t = 0; t < 8; ++t) m[t] = Mm[t0 + t][j];
#pragma unroll
      for (int i = 0; i < 4; ++i)
#pragma unroll
        for (int t = 0; t < 8; ++t) acc[i][t] += kk[i] * m[t];
    }
#pragma unroll
    for (int i = 0; i < 4; ++i) {
      float4 o0 = {acc[i][0], acc[i][1], acc[i][2], acc[i][3]};
      float4 o1 = {acc[i][4], acc[i][5], acc[i][6], acc[i][7]};
      *(float4*)&WpT[cb * 8192 + (size_t)(r0 + i) * 64 + t0] = o0;
      *(float4*)&WpT[cb * 8192 + (size_t)(r0 + i) * 64 + t0 + 4] = o1;
    }
  }
  __syncthreads();

  float* QT = UB;
#pragma unroll
  for (int i = 0; i < 8; ++i) {
    int w = (i * 256 + tid) * 4;
    int tt = w >> 7, r = w & 127;
    float4 v = *(const float4*)&qn[(size_t)(t_base + tt) * 1024 + h * 128 + r];
    QT[(r + 0) * 68 + tt] = v.x; QT[(r + 1) * 68 + tt] = v.y;
    QT[(r + 2) * 68 + tt] = v.z; QT[(r + 3) * 68 + tt] = v.w;
  }
  __syncthreads();

  {
    const int t0 = (tid >> 4) * 4, j0 = (tid & 15) * 4;
    float acc[4][4] = {};
    for (int r = 0; r < 128; ++r) {
      float4 a = *(const float4*)&QT[r * 68 + t0];
      float4 b = *(const float4*)&KT[r][j0];
      float av[4] = {a.x, a.y, a.z, a.w};
      float bv[4] = {b.x, b.y, b.z, b.w};
#pragma unroll
      for (int i = 0; i < 4; ++i)
#pragma unroll
        for (int j = 0; j < 4; ++j) acc[i][j] += av[i] * bv[j];
    }
#pragma unroll
    for (int i = 0; i < 4; ++i)
#pragma unroll
      for (int j = 0; j < 4; ++j) {
        int t = t0 + i, jj = j0 + j;
        BqT[cb * 4096 + (size_t)jj * 64 + t] =
            (jj <= t) ? expf(c_l[t] - c_l[jj]) * acc[i][j] : 0.f;
      }
  }
#pragma unroll
  for (int i = 0; i < 8; ++i) {
    int w = (i * 256 + tid) * 4;
    int r = w >> 6, t = w & 63;
    float4 q = *(const float4*)&QT[r * 68 + t];
    float4 s = *(const float4*)&seQ[t];
    q.x *= s.x; q.y *= s.y; q.z *= s.z; q.w *= s.w;
    *(float4*)&Qdt[cb * 8192 + w] = q;
  }
#pragma unroll
  for (int i = 0; i < 8; ++i) {
    int w = (i * 256 + tid) * 4;
    int t = w >> 7, r = w & 127;
    float s = sKd[t];
    float4 o;
    o.x = KT[r + 0][t] * s; o.y = KT[r + 1][t] * s;
    o.z = KT[r + 2][t] * s; o.w = KT[r + 3][t] * s;
    *(float4*)&Kdm[cb * 8192 + w] = o;
  }
}

// Precompute affine form: T = dC*I - Kd^T W^T  (stored [k][r]),
//                         b = Kd^T Upre        (stored [c][r]).
// grid: (mode 0..3, ch 32, h 8). mode 0/1 = T r-halves, 2/3 = b r-halves.
__global__ __launch_bounds__(256) void k_chunkT(
    const float* __restrict__ WpT, const float* __restrict__ Kdm,
    const float* __restrict__ Upre, const float* __restrict__ dec,
    float* __restrict__ Tc, float* __restrict__ bcb) {
  const int mode = blockIdx.x;
  const int ch = blockIdx.y;
  const int h = blockIdx.z;
  const int tid = threadIdx.x;
  const size_t cb = (size_t)h * NC + ch;
  const int rbase = (mode & 1) * 64;
  const bool isT = mode < 2;
  __shared__ float Ms[64 * 132];
  if (isT) {
    // Ms[t][k] = WpT[k][t]
#pragma unroll
    for (int i = 0; i < 8; ++i) {
      int idx = i * 256 + tid;
      int k = idx >> 4;
      int t0 = (idx & 15) * 4;
      float4 v = *(const float4*)&WpT[cb * 8192 + (size_t)k * 64 + t0];
      Ms[(t0 + 0) * 132 + k] = v.x;
      Ms[(t0 + 1) * 132 + k] = v.y;
      Ms[(t0 + 2) * 132 + k] = v.z;
      Ms[(t0 + 3) * 132 + k] = v.w;
    }
  } else {
    // Ms[t][c] = Upre[t][c]
#pragma unroll
    for (int i = 0; i < 8; ++i) {
      int idx = i * 256 + tid;
      int t = idx >> 5;
      int c0 = (idx & 31) * 4;
      *(float4*)&Ms[t * 132 + c0] =
          *(const float4*)&Upre[cb * 8192 + (size_t)t * 128 + c0];
    }
  }
  __syncthreads();
  const int rr = rbase + (tid >> 4) * 4;
  const int m0 = (tid & 15) * 8;
  float acc[4][8] = {};
#pragma unroll 2
  for (int t = 0; t < 64; ++t) {
    float4 kd = *(const float4*)&Kdm[cb * 8192 + (size_t)t * 128 + rr];
    float kv[4] = {kd.x, kd.y, kd.z, kd.w};
    float4 ma = *(const float4*)&Ms[t * 132 + m0];
    float4 mb = *(const float4*)&Ms[t * 132 + m0 + 4];
    float mv[8] = {ma.x, ma.y, ma.z, ma.w, mb.x, mb.y, mb.z, mb.w};
#pragma unroll
    for (int i = 0; i < 4; ++i)
#pragma unroll
      for (int j = 0; j < 8; ++j) acc[i][j] += kv[i] * mv[j];
  }
  if (isT) {
    const float dC = dec[cb];
#pragma unroll
    for (int j = 0; j < 8; ++j) {
      int k = m0 + j;
      float4 v;
      v.x = ((rr + 0) == k ? dC : 0.f) - acc[0][j];
      v.y = ((rr + 1) == k ? dC : 0.f) - acc[1][j];
      v.z = ((rr + 2) == k ? dC : 0.f) - acc[2][j];
      v.w = ((rr + 3) == k ? dC : 0.f) - acc[3][j];
      *(float4*)&Tc[cb * 16384 + (size_t)k * 128 + rr] = v;
    }
  } else {
#pragma unroll
    for (int j = 0; j < 8; ++j) {
      float4 v = {acc[0][j], acc[1][j], acc[2][j], acc[3][j]};
      *(float4*)&bcb[cb * 16384 + (size_t)(m0 + j) * 128 + rr] = v;
    }
  }
}

// Sequential scan: S' = T S + b per chunk. 128 blocks = 8h x 16cg (8 cols).
// Stores S_start per chunk to Sg ([c][r] layout). T read from global (L2).
__global__ __launch_bounds__(256) void k_chunkS2(
    const float* __restrict__ Tc, const float* __restrict__ bcb,
    float* __restrict__ Sg0, float* __restrict__ Sg1) {
  const int h = blockIdx.x >> 4;
  const int cg = blockIdx.x & 15;
  const int tid = threadIdx.x;
  const int cl = tid & 7;
  const int cglob = cg * 8 + cl;
  const int r0 = (tid >> 3) * 4;
  __shared__ float Sm[128 * 9];
  float s0 = 0.f, s1 = 0.f, s2 = 0.f, s3 = 0.f;
  Sm[(r0 + 0) * 9 + cl] = 0.f; Sm[(r0 + 1) * 9 + cl] = 0.f;
  Sm[(r0 + 2) * 9 + cl] = 0.f; Sm[(r0 + 3) * 9 + cl] = 0.f;
  __syncthreads();
  float* Sgb = (h < 4) ? (Sg0 + (size_t)h * NC * 16384)
                       : (Sg1 + (size_t)(h - 4) * NC * 16384);
  for (int ch = 0; ch < NC; ++ch) {
    const size_t cb = (size_t)h * NC + ch;
    float4 sv = {s0, s1, s2, s3};
    *(float4*)&Sgb[(size_t)ch * 16384 + (size_t)cglob * 128 + r0] = sv;
    float4 a = *(const float4*)&bcb[cb * 16384 + (size_t)cglob * 128 + r0];
    float a0 = a.x, a1 = a.y, a2 = a.z, a3 = a.w;
    const float* Tp = Tc + cb * 16384;
#pragma unroll 4
    for (int k = 0; k < 128; ++k) {
      float4 tv = *(const float4*)&Tp[(size_t)k * 128 + r0];
      float skc = Sm[k * 9 + cl];
      a0 += tv.x * skc; a1 += tv.y * skc; a2 += tv.z * skc; a3 += tv.w * skc;
    }
    __syncthreads();
    Sm[(r0 + 0) * 9 + cl] = a0; Sm[(r0 + 1) * 9 + cl] = a1;
    Sm[(r0 + 2) * 9 + cl] = a2; Sm[(r0 + 3) * 9 + cl] = a3;
    s0 = a0; s1 = a1; s2 = a2; s3 = a3;
    __syncthreads();
  }
}

// Parallel output kernel: grid (cg 8, ch 32, h 8).
// u = Upre - W^T S_start; O = Qd^T S_start + Bq^T u.
__global__ __launch_bounds__(256) void k_chunkO(
    const float* __restrict__ Upre, const float* __restrict__ WpT,
    const float* __restrict__ Qdt, const float* __restrict__ BqT,
    const float* __restrict__ Sg0, const float* __restrict__ Sg1,
    float* __restrict__ core) {
  const int cg = blockIdx.x;
  const int ch = blockIdx.y;
  const int h = blockIdx.z;
  const int cbase = cg * 16;
  const int tid = threadIdx.x;

  __shared__ float Sm[128][20];
  __shared__ float um[64][20];
  __shared__ float buf[128 * 68];
  __shared__ float Bs[64][68];

  const size_t cb = (size_t)h * NC + ch;
  const float* Up = Upre + cb * 8192;
  const float* Sc = ((h < 4) ? (Sg0 + (size_t)h * NC * 16384)
                             : (Sg1 + (size_t)(h - 4) * NC * 16384))
                    + (size_t)ch * 16384;

  // load S_start from [c][r] layout
  {
    int c = tid & 15;
    int rr = (tid >> 4) * 8;
    float4 v0 = *(const float4*)&Sc[(size_t)(cbase + c) * 128 + rr];
    float4 v1 = *(const float4*)&Sc[(size_t)(cbase + c) * 128 + rr + 4];
    Sm[rr + 0][c] = v0.x; Sm[rr + 1][c] = v0.y;
    Sm[rr + 2][c] = v0.z; Sm[rr + 3][c] = v0.w;
    Sm[rr + 4][c] = v1.x; Sm[rr + 5][c] = v1.y;
    Sm[rr + 6][c] = v1.z; Sm[rr + 7][c] = v1.w;
  }
  // stage Wp, Bq
  {
    const float* Wp = WpT + cb * 8192;
    const float* Bp = BqT + cb * 4096;
#pragma unroll
    for (int i = 0; i < 8; ++i) {
      int w = (i * 256 + tid) * 4;
      *(float4*)&buf[(w >> 6) * 68 + (w & 63)] = *(const float4*)&Wp[w];
    }
#pragma unroll
    for (int i = 0; i < 4; ++i) {
      int w = (i * 256 + tid) * 4;
      *(float4*)&Bs[w >> 6][w & 63] = *(const float4*)&Bp[w];
    }
  }
  __syncthreads();

  const int t0 = (tid >> 3) * 2;
  const int cc = (tid & 7) * 2;

  // u
  {
    float a00 = 0, a01 = 0, a10 = 0, a11 = 0;
#pragma unroll 4
    for (int r = 0; r < 128; ++r) {
      float2 wv = *(const float2*)&buf[r * 68 + t0];
      float2 sv = *(const float2*)&Sm[r][cc];
      a00 += wv.x * sv.x; a01 += wv.x * sv.y;
      a10 += wv.y * sv.x; a11 += wv.y * sv.y;
    }
    float2 u0 = *(const float2*)&Up[(size_t)t0 * 128 + cbase + cc];
    float2 u1 = *(const float2*)&Up[(size_t)(t0 + 1) * 128 + cbase + cc];
    u0.x -= a00; u0.y -= a01;
    u1.x -= a10; u1.y -= a11;
    *(float2*)&um[t0][cc] = u0;
    *(float2*)&um[t0 + 1][cc] = u1;
  }
  __syncthreads();

  // stage Qd
  {
    const float* Qp = Qdt + cb * 8192;
#pragma unroll
    for (int i = 0; i < 8; ++i) {
      int w = (i * 256 + tid) * 4;
      *(float4*)&buf[(w >> 6) * 68 + (w & 63)] = *(const float4*)&Qp[w];
    }
  }
  __syncthreads();

  // O
  {
    float a00 = 0, a01 = 0, a10 = 0, a11 = 0;
#pragma unroll 4
    for (int r = 0; r < 128; ++r) {
      float2 qv = *(const float2*)&buf[r * 68 + t0];
      float2 sv = *(const float2*)&Sm[r][cc];
      a00 += qv.x * sv.x; a01 += qv.x * sv.y;
      a10 += qv.y * sv.x; a11 += qv.y * sv.y;
    }
#pragma unroll 4
    for (int j = 0; j < 64; ++j) {
      float2 bv = *(const float2*)&Bs[j][t0];
      float2 uv = *(const float2*)&um[j][cc];
      a00 += bv.x * uv.x; a01 += bv.x * uv.y;
      a10 += bv.y * uv.x; a11 += bv.y * uv.y;
    }
    float2 o0 = {a00, a01}, o1 = {a10, a11};
    *(float2*)&core[(size_t)(ch * 64 + t0) * 1024 + h * 128 + cbase + cc] = o0;
    *(float2*)&core[(size_t)(ch * 64 + t0 + 1) * 1024 + h * 128 + cbase + cc] = o1;
  }
}

// ---------------- gated RMSNorm per value head * silu(z); in-place safe (f32)
__global__ __launch_bounds__(256) void k_gatenorm(const float* __restrict__ core,
                                                  const float* __restrict__ qkvz,
                                                  const float* __restrict__ gnw,
                                                  float* __restrict__ y) {
  const int t = blockIdx.x, tid = threadIdx.x;
  const int wave = tid >> 6, lane = tid & 63;
  const int h = blockIdx.y * 4 + wave;
  const float* cbp = core + (size_t)t * 1024 + h * DV;
  float c0 = cbp[lane], c1 = cbp[lane + 64];
  float ss = c0 * c0 + c1 * c1;
  for (int m = 1; m < 64; m <<= 1) ss += __shfl_xor(ss, m);
  float scale = 1.f / sqrtf(ss * (1.0f / DV) + EPS);
  const float* zb = qkvz + (size_t)t * QKVZ_N + 2 * KEY_DIM + VAL_DIM + h * DV;
  float z0 = zb[lane], z1 = zb[lane + 64];
  float g0 = gnw[lane], g1 = gnw[lane + 64];
  float o0 = c0 * scale * g0 * (z0 / (1.f + expf(-z0)));
  float o1 = c1 * scale * g1 * (z1 / (1.f + expf(-z1)));
  float* yb = y + (size_t)t * 1024 + h * DV;
  yb[lane] = o0; yb[lane + 64] = o1;
}

// ---------------- router
__global__ __launch_bounds__(256) void k_router(const float* __restrict__ x2,
                                                const float* __restrict__ Wr,
                                                float* __restrict__ rinfo,
                                                int* __restrict__ cnt,
                                                float* __restrict__ outTopi) {
  const int t = blockIdx.x, tid = threadIdx.x;
  const int n = tid >> 5, kl = tid & 31;
  const float* xr = x2 + (size_t)t * HID;
  float s = 0.f;
  for (int k = kl; k < HID; k += 32) s += xr[k] * Wr[k * 8 + n];
  for (int m = 1; m < 32; m <<= 1) s += __shfl_xor(s, m);
  __shared__ float lg[8];
  if (kl == 0) lg[n] = s;
  __syncthreads();
  if (tid == 0) {
    int i0 = 0; float m0 = lg[0];
    for (int e = 1; e < 8; ++e) if (lg[e] > m0) { m0 = lg[e]; i0 = e; }
    int i1 = -1; float m1 = -1e30f;
    for (int e = 0; e < 8; ++e) if (e != i0 && lg[e] > m1) { m1 = lg[e]; i1 = e; }
    float e1 = expf(m1 - m0);
    float w0 = 1.f / (1.f + e1);
    float w1 = e1 / (1.f + e1);
    rinfo[t * 4 + 0] = (float)i0; rinfo[t * 4 + 1] = (float)i1;
    rinfo[t * 4 + 2] = w0;        rinfo[t * 4 + 3] = w1;
    atomicAdd(&cnt[i0], 1);
    atomicAdd(&cnt[i1], 1);
    outTopi[t * 2 + 0] = (float)i0;
    outTopi[t * 2 + 1] = (float)i1;
  }
}

__global__ void k_offsets(const int* __restrict__ cnt, int* __restrict__ offs,
                          int* __restrict__ cnt2) {
  if (threadIdx.x == 0) {
    int a = 0;
    for (int e = 0; e < 8; ++e) { offs[e] = a; a += cnt[e]; cnt2[e] = 0; }
  }
}

__global__ __launch_bounds__(256) void k_scatter(const float* __restrict__ rinfo,
                                                 const int* __restrict__ offs,
                                                 int* __restrict__ cnt2,
                                                 int* __restrict__ pairTok,
                                                 int* __restrict__ tokPos) {
  int t = blockIdx.x * 256 + threadIdx.x;
  if (t >= S) return;
  int i0 = (int)rinfo[t * 4 + 0], i1 = (int)rinfo[t * 4 + 1];
  int p0 = offs[i0] + atomicAdd(&cnt2[i0], 1);
  pairTok[p0] = t;
  int p1 = offs[i1] + atomicAdd(&cnt2[i1], 1);
  pairTok[p1] = t;
  tokPos[t * 2 + 0] = p0;
  tokPos[t * 2 + 1] = p1;
}

// ---------------- MoE stage 1 (MFMA bf16)
__global__ __launch_bounds__(256) void k_moe1m(const u16* __restrict__ x2b,
                                               const u16* __restrict__ WgT,
                                               const u16* __restrict__ WuT,
                                               const int* __restrict__ offs,
                                               const int* __restrict__ cnt,
                                               const int* __restrict__ pairTok,
                                               u16* __restrict__ act) {
  const int e = blockIdx.z;
  const int count = cnt[e];
  const int m0 = blockIdx.y * 128;
  if (m0 >= count) return;
  const int base = offs[e];
  __shared__ u16 Abuf[4096], Gbuf[4096], Ubuf[4096];
  const int tid = threadIdx.x;
  const int lane = tid & 63, wave = tid >> 6;
  const int wm = wave >> 1, wn = wave & 1;
  const int n0 = blockIdx.x * 128;
  const int wb0 = wave * 512, wb1 = 2048 + wave * 512;
  const int r0 = tid >> 2;
  int mr0 = m0 + r0;       if (mr0 > count - 1) mr0 = count - 1;
  int mr1 = m0 + r0 + 64;  if (mr1 > count - 1) mr1 = count - 1;
  const int t0tok = pairTok[base + mr0];
  const int t1tok = pairTok[base + mr1];
  const u16* Ag0 = x2b + (size_t)t0tok * 1024 + (tid & 3) * 8;
  const u16* Ag1 = x2b + (size_t)t1tok * 1024 + (tid & 3) * 8;
  const u16* Gg0 = WgT + (size_t)e * 512 * 1024 + (size_t)(n0 + r0) * 1024 + (tid & 3) * 8;
  const u16* Gg1 = Gg0 + (size_t)64 * 1024;
  const u16* Ug0 = WuT + (size_t)e * 512 * 1024 + (size_t)(n0 + r0) * 1024 + (tid & 3) * 8;
  const u16* Ug1 = Ug0 + (size_t)64 * 1024;
  f32x4 ag[4][4] = {}, au[4][4] = {};
  const int fr = lane & 15, kg = lane >> 4;
  for (int k0 = 0; k0 < 1024; k0 += 32) {
    gload16(Ag0 + k0, Abuf + wb0);
    gload16(Ag1 + k0, Abuf + wb1);
    gload16(Gg0 + k0, Gbuf + wb0);
    gload16(Gg1 + k0, Gbuf + wb1);
    gload16(Ug0 + k0, Ubuf + wb0);
    gload16(Ug1 + k0, Ubuf + wb1);
    __syncthreads();
    bf16x8 af[4], gf[4], uf[4];
#pragma unroll
    for (int i = 0; i < 4; ++i) {
      af[i] = *(const bf16x8*)&Abuf[(wm * 64 + i * 16 + fr) * 32 + kg * 8];
      gf[i] = *(const bf16x8*)&Gbuf[(wn * 64 + i * 16 + fr) * 32 + kg * 8];
      uf[i] = *(const bf16x8*)&Ubuf[(wn * 64 + i * 16 + fr) * 32 + kg * 8];
    }
#pragma unroll
    for (int i = 0; i < 4; ++i)
#pragma unroll
      for (int j = 0; j < 4; ++j) {
        ag[i][j] = __builtin_amdgcn_mfma_f32_16x16x32_bf16(af[i], gf[j], ag[i][j], 0, 0, 0);
        au[i][j] = __builtin_amdgcn_mfma_f32_16x16x32_bf16(af[i], uf[j], au[i][j], 0, 0, 0);
      }
    __syncthreads();
  }
#pragma unroll
  for (int i = 0; i < 4; ++i) {
#pragma unroll
    for (int j = 0; j < 4; ++j) {
      int rowt = wm * 64 + i * 16 + kg * 4;
      int col = n0 + wn * 64 + j * 16 + fr;
#pragma unroll
      for (int r = 0; r < 4; ++r) {
        if (m0 + rowt + r < count) {
          float g = ag[i][j][r], u = au[i][j][r];
          act[(size_t)(base + m0 + rowt + r) * 512 + col] =
              f2b(g / (1.f + expf(-g)) * u);
        }
      }
    }
  }
}

// ---------------- MoE stage 2 (MFMA bf16): eo = act @ Wd[e]
__global__ __launch_bounds__(256) void k_moe2m(const u16* __restrict__ act,
                                               const u16* __restrict__ WdT,
                                               const int* __restrict__ offs,
                                               const int* __restrict__ cnt,
                                               float* __restrict__ eo) {
  const int e = blockIdx.z;
  const int count = cnt[e];
  const int m0 = blockIdx.y * 128;
  if (m0 >= count) return;
  const int base = offs[e];
  __shared__ u16 Abuf[4096], Bbuf[4096];
  const int tid = threadIdx.x;
  const int lane = tid & 63, wave = tid >> 6;
  const int wm = wave >> 1, wn = wave & 1;
  const int n0 = blockIdx.x * 128;
  const int wb0 = wave * 512, wb1 = 2048 + wave * 512;
  const int r0 = tid >> 2;
  int mr0 = m0 + r0;       if (mr0 > count - 1) mr0 = count - 1;
  int mr1 = m0 + r0 + 64;  if (mr1 > count - 1) mr1 = count - 1;
  const u16* Ag0 = act + (size_t)(base + mr0) * 512 + (tid & 3) * 8;
  const u16* Ag1 = act + (size_t)(base + mr1) * 512 + (tid & 3) * 8;
  const u16* Bg0 = WdT + (size_t)e * 1024 * 512 + (size_t)(n0 + r0) * 512 + (tid & 3) * 8;
  const u16* Bg1 = Bg0 + (size_t)64 * 512;
  f32x4 acc[4][4] = {};
  const int fr = lane & 15, kg = lane >> 4;
  for (int k0 = 0; k0 < 512; k0 += 32) {
    gload16(Ag0 + k0, Abuf + wb0);
    gload16(Ag1 + k0, Abuf + wb1);
    gload16(Bg0 + k0, Bbuf + wb0);
    gload16(Bg1 + k0, Bbuf + wb1);
    __syncthreads();
    bf16x8 af[4], bfr[4];
#pragma unroll
    for (int i = 0; i < 4; ++i) {
      af[i]  = *(const bf16x8*)&Abuf[(wm * 64 + i * 16 + fr) * 32 + kg * 8];
      bfr[i] = *(const bf16x8*)&Bbuf[(wn * 64 + i * 16 + fr) * 32 + kg * 8];
    }
#pragma unroll
    for (int i = 0; i < 4; ++i)
#pragma unroll
      for (int j = 0; j < 4; ++j)
        acc[i][j] = __builtin_amdgcn_mfma_f32_16x16x32_bf16(af[i], bfr[j], acc[i][j], 0, 0, 0);
    __syncthreads();
  }
#pragma unroll
  for (int i = 0; i < 4; ++i) {
#pragma unroll
    for (int j = 0; j < 4; ++j) {
      int rowt = wm * 64 + i * 16 + kg * 4;
      int col = n0 + wn * 64 + j * 16 + fr;
#pragma unroll
      for (int r = 0; r < 4; ++r) {
        if (m0 + rowt + r < count)
          eo[(size_t)(base + m0 + rowt + r) * 1024 + col] = acc[i][j][r];
      }
    }
  }
}

// ---------------- final: out[t] += w0*eo[p0] + w1*eo[p1]
__global__ __launch_bounds__(256) void k_finish(const float* __restrict__ eo,
                                                const int* __restrict__ tokPos,
                                                const float* __restrict__ rinfo,
                                                float* __restrict__ out) {
  const int t = blockIdx.x;
  const int c = threadIdx.x * 4;
  float w0 = rinfo[t * 4 + 2], w1 = rinfo[t * 4 + 3];
  int p0 = tokPos[t * 2 + 0], p1 = tokPos[t * 2 + 1];
  float4 a = *(const float4*)&eo[(size_t)p0 * 1024 + c];
  float4 b = *(const float4*)&eo[(size_t)p1 * 1024 + c];
  float4 o = *(const float4*)&out[(size_t)t * 1024 + c];
  o.x += w0 * a.x + w1 * b.x;
  o.y += w0 * a.y + w1 * b.y;
  o.z += w0 * a.z + w1 * b.z;
  o.w += w0 * a.w + w1 * b.w;
  *(float4*)&out[(size_t)t * 1024 + c] = o;
}

extern "C" void kernel_launch(void* const* d_in, const int* in_sizes, int n_in,
                              void* d_out, int out_size, void* d_ws, size_t ws_size,
                              hipStream_t stream) {
  const float* hid      = (const float*)d_in[0];
  const float* w_ln1    = (const float*)d_in[1];
  const float* w_ln2    = (const float*)d_in[2];
  const float* W_qkvz   = (const float*)d_in[3];
  const float* W_ba     = (const float*)d_in[4];
  const float* conv_w   = (const float*)d_in[5];
  const float* dt_bias  = (const float*)d_in[6];
  const float* A_log    = (const float*)d_in[7];
  const float* gnw      = (const float*)d_in[8];
  const float* W_out    = (const float*)d_in[9];
  const float* W_router = (const float*)d_in[10];
  const float* W_gate   = (const float*)d_in[11];
  const float* W_up     = (const float*)d_in[12];
  const float* W_down   = (const float*)d_in[13];

  float* ws = (float*)d_ws;
  const size_t M1 = (size_t)1024 * 1024;
  float* x1    = ws;               // 2M (Sg0 during scan)
  float* qkvz  = x1 + 2 * M1;      // 6M
  float* conv  = qkvz + 6 * M1;    // 4M (Tc during scan; WgT/WuT after)
  float* qn    = conv + 4 * M1;    // 2M ┐ bc (4M contiguous)
  float* kn    = qn + 2 * M1;      // 2M ┘ (WdT after scan)
  float* core  = kn + 2 * M1;      // 2M
  float* Upre  = core + 2 * M1;    // 2M
  float* WpT   = Upre + 2 * M1;    // 2M
  float* Qdt   = WpT + 2 * M1;     // 2M
  float* Kdm   = Qdt + 2 * M1;     // 2M (act after scan)
  float* BqT   = Kdm + 2 * M1;     // 1M
  float* Sg1   = BqT + M1;         // 2M (heads 4-7 S_start)
  float* dec   = Sg1 + 2 * M1;     // 256
  float* ba    = dec + 256;        // 32768
  float* gb    = ba + 32768;       // 16384
  float* betab = gb + 16384;       // 16384
  float* rinfo = betab + 16384;    // 8192
  int*   ints  = (int*)(rinfo + 8192);
  int* cnt     = ints;             // 8
  int* cnt2    = ints + 8;         // 8
  int* offs    = ints + 16;        // 8
  int* pairTok = ints + 32;        // 4096
  int* tokPos  = ints + 4128;      // 4096
  u16* x1b     = (u16*)(ints + 8224);  // 2M u16

  float* Tc  = conv;               // 4M (after chunkA, before transposes)
  float* bcb = qn;                 // 4M (spans qn+kn)
  float* Sg0 = x1;                 // 2M (heads 0-3)
  u16* WgT = (u16*)conv;           // after chunkS2
  u16* WuT = (u16*)(conv + 2 * M1);
  u16* WdT = (u16*)kn;
  u16* act = (u16*)Kdm;            // after chunkT
  float* eo = Upre;                // 4M spans Upre+WpT (after chunkO+W_out... used by moe2m)

  float* outF = (float*)d_out;
  const size_t N1 = (size_t)S * HID;

  hipMemsetAsync(cnt, 0, 16 * sizeof(int), stream);

  k_rms<<<S, 256, 0, stream>>>(hid, w_ln1, x1, x1b);
  k_sgemm2<<<dim3(24, 16), 256, 0, stream>>>(x1, W_qkvz, nullptr, qkvz, S, QKVZ_N, HID);
  k_ba<<<S, 256, 0, stream>>>(x1, W_ba, ba);
  k_bg<<<(S * HV + 255) / 256, 256, 0, stream>>>(ba, dt_bias, A_log, gb, betab);
  k_conv<<<(S * CONV_DIM) / 256, 256, 0, stream>>>(qkvz, conv_w, conv);
  k_prep<<<S, 512, 0, stream>>>(conv, qn, kn);
  k_chunkA<<<HV * NC, 256, 0, stream>>>(qn, kn, conv, gb, betab,
                                        Upre, WpT, Qdt, Kdm, BqT, dec);
  // conv/qn/kn dead -> T-form precompute + sequential scan
  k_chunkT<<<dim3(4, 32, 8), 256, 0, stream>>>(WpT, Kdm, Upre, dec, Tc, bcb);
  k_chunkS2<<<128, 256, 0, stream>>>(Tc, bcb, Sg0, Sg1);
  // Tc/bc dead -> MoE bf16 weights
  k_transp<<<dim3(16, 32, 8), 256, 0, stream>>>(W_gate, WgT, 1024, 512);
  k_transp<<<dim3(16, 32, 8), 256, 0, stream>>>(W_up, WuT, 1024, 512);
  k_transp<<<dim3(32, 16, 8), 256, 0, stream>>>(W_down, WdT, 512, 1024);
  k_chunkO<<<dim3(8, 32, 8), 256, 0, stream>>>(Upre, WpT, Qdt, BqT, Sg0, Sg1, core);
  k_gatenorm<<<dim3(S, 2), 256, 0, stream>>>(core, qkvz, gnw, core);
  k_sgemm2<<<dim3(8, 16), 256, 0, stream>>>(core, W_out, hid, outF, S, HID, VAL_DIM);
  k_rms<<<S, 256, 0, stream>>>(outF, w_ln2, x1, x1b);
  k_router<<<S, 256, 0, stream>>>(x1, W_router, rinfo, cnt, outF + N1);
  k_offsets<<<1, 64, 0, stream>>>(cnt, offs, cnt2);
  k_scatter<<<(S + 255) / 256, 256, 0, stream>>>(rinfo, offs, cnt2, pairTok, tokPos);
  k_moe1m<<<dim3(4, 32, 8), 256, 0, stream>>>(x1b, WgT, WuT, offs, cnt, pairTok, act);
  k_moe2m<<<dim3(8, 32, 8), 256, 0, stream>>>(act, WdT, offs, cnt, eo);
  k_finish<<<S, 256, 0, stream>>>(eo, tokPos, rinfo, outF);
}

// Round 9
// 1023.931 us; speedup vs baseline: 1.1028x; 1.1028x over previous
//
#include <hip/hip_runtime.h>

#define S 2048
#define HID 1024
#define HK 4
#define HV 8
#define DK 128
#define DV 128
#define KEY_DIM 512
#define VAL_DIM 1024
#define CONV_DIM 2048
#define QKVZ_N 3072
#define NEXP 8
#define INTER 512
#define EPS 1e-6f
#define CK 64
#define NC 32

typedef unsigned short u16;
typedef unsigned int u32;
typedef __attribute__((ext_vector_type(8))) short bf16x8;
typedef __attribute__((ext_vector_type(4))) float f32x4;

__device__ __forceinline__ u16 f2b(float f) {
  u32 u = __builtin_bit_cast(u32, f);
  u += 0x7fff + ((u >> 16) & 1);
  return (u16)(u >> 16);
}

__device__ __forceinline__ void gload16(const u16* g, u16* l) {
  __builtin_amdgcn_global_load_lds(
      (const __attribute__((address_space(1))) void*)g,
      (__attribute__((address_space(3))) void*)l, 16, 0, 0);
}

// ---------------- zero-centered RMSNorm -> f32 out + bf16 out
__global__ __launch_bounds__(256) void k_rms(const float* __restrict__ x,
                                             const float* __restrict__ w,
                                             float* __restrict__ out,
                                             u16* __restrict__ outb) {
  const int row = blockIdx.x;
  const int tid = threadIdx.x;
  const float* xr = x + (size_t)row * HID;
  float4 v = ((const float4*)xr)[tid];
  float ss = v.x*v.x + v.y*v.y + v.z*v.z + v.w*v.w;
  for (int m = 1; m < 64; m <<= 1) ss += __shfl_xor(ss, m);
  __shared__ float sred[4];
  if ((tid & 63) == 0) sred[tid >> 6] = ss;
  __syncthreads();
  float tot = sred[0] + sred[1] + sred[2] + sred[3];
  float scale = 1.0f / sqrtf(tot * (1.0f / HID) + EPS);
  float4 wv = ((const float4*)w)[tid];
  float4 o;
  o.x = v.x * scale * (1.0f + wv.x);
  o.y = v.y * scale * (1.0f + wv.y);
  o.z = v.z * scale * (1.0f + wv.z);
  o.w = v.w * scale * (1.0f + wv.w);
  ((float4*)(out + (size_t)row * HID))[tid] = o;
  u32 p0 = (u32)f2b(o.x) | ((u32)f2b(o.y) << 16);
  u32 p1 = (u32)f2b(o.z) | ((u32)f2b(o.w) << 16);
  *(uint2*)&outb[(size_t)row * HID + tid * 4] = make_uint2(p0, p1);
}

// ---------------- transpose+cast: src f32 [K][N] -> dst bf16 [N][K], batched z
__global__ __launch_bounds__(256) void k_transp(const float* __restrict__ src,
                                                u16* __restrict__ dst,
                                                int K, int N) {
  __shared__ float t[32][33];
  const size_t bo = (size_t)blockIdx.z * K * N;
  src += bo; dst += bo;
  int n0 = blockIdx.x * 32, k0 = blockIdx.y * 32;
  int tx = threadIdx.x & 31, ty = threadIdx.x >> 5;
#pragma unroll
  for (int i = 0; i < 32; i += 8)
    t[ty + i][tx] = src[(size_t)(k0 + ty + i) * N + n0 + tx];
  __syncthreads();
#pragma unroll
  for (int i = 0; i < 32; i += 8)
    dst[(size_t)(n0 + ty + i) * K + k0 + tx] = f2b(t[tx][ty + i]);
}

// ---------------- f32 GEMM 128x128 tile, 8x8/thread, reg-double-buffered
__global__ __launch_bounds__(256) void k_sgemm2(const float* __restrict__ A,
                                                const float* __restrict__ B,
                                                const float* __restrict__ Cadd,
                                                float* __restrict__ C,
                                                int M, int N, int K) {
  __shared__ float As[16][132];
  __shared__ float Bs[16][132];
  const int tid = threadIdx.x;
  const int ty = tid >> 4, tx = tid & 15;
  const int m0 = blockIdx.y * 128, n0 = blockIdx.x * 128;
  const int ar = tid >> 1, ak = (tid & 1) * 8;
  const int br = tid >> 4, bc = (tid & 15) * 8;
  float acc[8][8] = {};
  float4 ra0, ra1, rb0, rb1;
  ra0 = *(const float4*)&A[(size_t)(m0 + ar) * K + ak];
  ra1 = *(const float4*)&A[(size_t)(m0 + ar) * K + ak + 4];
  rb0 = *(const float4*)&B[(size_t)br * N + n0 + bc];
  rb1 = *(const float4*)&B[(size_t)br * N + n0 + bc + 4];
  for (int k0 = 0; k0 < K; k0 += 16) {
    As[ak + 0][ar] = ra0.x; As[ak + 1][ar] = ra0.y;
    As[ak + 2][ar] = ra0.z; As[ak + 3][ar] = ra0.w;
    As[ak + 4][ar] = ra1.x; As[ak + 5][ar] = ra1.y;
    As[ak + 6][ar] = ra1.z; As[ak + 7][ar] = ra1.w;
    *(float4*)&Bs[br][bc]     = rb0;
    *(float4*)&Bs[br][bc + 4] = rb1;
    __syncthreads();
    if (k0 + 16 < K) {
      ra0 = *(const float4*)&A[(size_t)(m0 + ar) * K + k0 + 16 + ak];
      ra1 = *(const float4*)&A[(size_t)(m0 + ar) * K + k0 + 16 + ak + 4];
      rb0 = *(const float4*)&B[(size_t)(k0 + 16 + br) * N + n0 + bc];
      rb1 = *(const float4*)&B[(size_t)(k0 + 16 + br) * N + n0 + bc + 4];
    }
#pragma unroll
    for (int kk = 0; kk < 16; ++kk) {
      float4 aA = *(const float4*)&As[kk][ty * 8];
      float4 aB = *(const float4*)&As[kk][ty * 8 + 4];
      float4 bA = *(const float4*)&Bs[kk][tx * 8];
      float4 bB = *(const float4*)&Bs[kk][tx * 8 + 4];
      float a[8] = {aA.x, aA.y, aA.z, aA.w, aB.x, aB.y, aB.z, aB.w};
      float b[8] = {bA.x, bA.y, bA.z, bA.w, bB.x, bB.y, bB.z, bB.w};
#pragma unroll
      for (int i = 0; i < 8; ++i)
#pragma unroll
        for (int j = 0; j < 8; ++j) acc[i][j] += a[i] * b[j];
    }
    __syncthreads();
  }
#pragma unroll
  for (int i = 0; i < 8; ++i) {
    size_t off = (size_t)(m0 + ty * 8 + i) * N + n0 + tx * 8;
    float4 o0 = {acc[i][0], acc[i][1], acc[i][2], acc[i][3]};
    float4 o1 = {acc[i][4], acc[i][5], acc[i][6], acc[i][7]};
    if (Cadd) {
      float4 c0 = *(const float4*)&Cadd[off];
      float4 c1 = *(const float4*)&Cadd[off + 4];
      o0.x += c0.x; o0.y += c0.y; o0.z += c0.z; o0.w += c0.w;
      o1.x += c1.x; o1.y += c1.y; o1.z += c1.z; o1.w += c1.w;
    }
    *(float4*)&C[off] = o0;
    *(float4*)&C[off + 4] = o1;
  }
}

// ---------------- ba = x1 @ W_ba  (N=16)
__global__ __launch_bounds__(256) void k_ba(const float* __restrict__ x1,
                                            const float* __restrict__ Wba,
                                            float* __restrict__ ba) {
  const int t = blockIdx.x, tid = threadIdx.x;
  const int n = tid >> 4, kl = tid & 15;
  const float* xr = x1 + (size_t)t * HID;
  float s = 0.f;
  for (int k = kl; k < HID; k += 16) s += xr[k] * Wba[k * 16 + n];
  for (int m = 1; m < 16; m <<= 1) s += __shfl_xor(s, m);
  if (kl == 0) ba[t * 16 + n] = s;
}

// ---------------- beta = sigmoid(b); g = -exp(A_log)*softplus(a+dt_bias)
__global__ __launch_bounds__(256) void k_bg(const float* __restrict__ ba,
                                            const float* __restrict__ dt_bias,
                                            const float* __restrict__ A_log,
                                            float* __restrict__ gb,
                                            float* __restrict__ beta) {
  int i = blockIdx.x * 256 + threadIdx.x;
  if (i >= S * HV) return;
  int t = i >> 3, h = i & 7;
  float b = ba[t * 16 + h];
  float a = ba[t * 16 + 8 + h];
  beta[i] = 1.f / (1.f + expf(-b));
  float x = a + dt_bias[h];
  float sp = fmaxf(x, 0.f) + log1pf(expf(-fabsf(x)));
  gb[i] = -expf(A_log[h]) * sp;
}

// ---------------- causal depthwise conv (K=4) + silu on qkvz cols [0,2048)
__global__ __launch_bounds__(256) void k_conv(const float* __restrict__ qkvz,
                                              const float* __restrict__ cw,
                                              float* __restrict__ conv) {
  int idx = blockIdx.x * 256 + threadIdx.x;
  int t = idx >> 11, c = idx & 2047;
  float4 w = ((const float4*)cw)[c];
  float acc = 0.f;
  if (t >= 3) {
    acc = qkvz[(size_t)(t - 3) * QKVZ_N + c] * w.x
        + qkvz[(size_t)(t - 2) * QKVZ_N + c] * w.y
        + qkvz[(size_t)(t - 1) * QKVZ_N + c] * w.z
        + qkvz[(size_t)(t    ) * QKVZ_N + c] * w.w;
  } else {
    if (t - 3 >= 0) acc += qkvz[(size_t)(t - 3) * QKVZ_N + c] * w.x;
    if (t - 2 >= 0) acc += qkvz[(size_t)(t - 2) * QKVZ_N + c] * w.y;
    if (t - 1 >= 0) acc += qkvz[(size_t)(t - 1) * QKVZ_N + c] * w.z;
    acc += qkvz[(size_t)t * QKVZ_N + c] * w.w;
  }
  conv[idx] = acc / (1.f + expf(-acc));
}

// ---------------- l2-normalize q,k per source head; repeat to 8 dest heads
__global__ __launch_bounds__(512) void k_prep(const float* __restrict__ conv,
                                              float* __restrict__ qn,
                                              float* __restrict__ kn) {
  const int t = blockIdx.x, tid = threadIdx.x;
  const int sh = tid >> 7;
  const int d = tid & 127;
  float qv = conv[(size_t)t * CONV_DIM + sh * DK + d];
  float kv = conv[(size_t)t * CONV_DIM + KEY_DIM + sh * DK + d];
  float sq = qv * qv, sk = kv * kv;
  for (int m = 1; m < 64; m <<= 1) { sq += __shfl_xor(sq, m); sk += __shfl_xor(sk, m); }
  __shared__ float rq[8], rk[8];
  const int wave = tid >> 6;
  if ((tid & 63) == 0) { rq[wave] = sq; rk[wave] = sk; }
  __syncthreads();
  float sumq = rq[sh * 2] + rq[sh * 2 + 1];
  float sumk = rk[sh * 2] + rk[sh * 2 + 1];
  float qs = (1.f / sqrtf(sumq + EPS)) * 0.08838834764831845f;
  float ks = 1.f / sqrtf(sumk + EPS);
  float qo = qv * qs, ko = kv * ks;
  size_t b0 = (size_t)t * 1024 + (size_t)(sh * 2) * DK + d;
  qn[b0] = qo; qn[b0 + DK] = qo;
  kn[b0] = ko; kn[b0 + DK] = ko;
}

// ================= chunked gated delta rule =================
__global__ __launch_bounds__(256) void k_chunkA(
    const float* __restrict__ qn, const float* __restrict__ kn,
    const float* __restrict__ conv, const float* __restrict__ gbuf,
    const float* __restrict__ betab,
    float* __restrict__ Upre, float* __restrict__ WpT,
    float* __restrict__ Qdt, float* __restrict__ Kdm,
    float* __restrict__ BqT, float* __restrict__ dec) {
  const int h = blockIdx.x >> 5;
  const int ch = blockIdx.x & 31;
  const int tid = threadIdx.x;
  const int t_base = ch * CK;

  __shared__ float KT[128][68];
  __shared__ float UB[8704];
  __shared__ float Am[64][68];
  __shared__ float Mm[64][68];
  __shared__ float c_l[64], b_l[64], sW[64], seQ[64], sKd[64];

#pragma unroll
  for (int i = 0; i < 8; ++i) {
    int w = (i * 256 + tid) * 4;
    int tt = w >> 7, r = w & 127;
    float4 v = *(const float4*)&kn[(size_t)(t_base + tt) * 1024 + h * 128 + r];
    KT[r + 0][tt] = v.x; KT[r + 1][tt] = v.y; KT[r + 2][tt] = v.z; KT[r + 3][tt] = v.w;
  }
  if (tid < 64) {
    c_l[tid] = gbuf[(t_base + tid) * HV + h];
    b_l[tid] = betab[(t_base + tid) * HV + h];
  }
  __syncthreads();
  if (tid == 0) {
    float run = 0.f;
    for (int t = 0; t < 64; ++t) { run += c_l[t]; c_l[t] = run; }
    dec[h * NC + ch] = expf(run);
  }
  __syncthreads();
  if (tid < 64) {
    sW[tid] = b_l[tid] * expf(c_l[tid]);
    seQ[tid] = expf(c_l[tid]);
    sKd[tid] = expf(c_l[63] - c_l[tid]);
  }
  __syncthreads();

  {
    const int t0 = (tid >> 4) * 4, j0 = (tid & 15) * 4;
    float acc[4][4] = {};
    for (int r = 0; r < 128; ++r) {
      float4 a = *(const float4*)&KT[r][t0];
      float4 b = *(const float4*)&KT[r][j0];
      float av[4] = {a.x, a.y, a.z, a.w};
      float bv[4] = {b.x, b.y, b.z, b.w};
#pragma unroll
      for (int i = 0; i < 4; ++i)
#pragma unroll
        for (int j = 0; j < 4; ++j) acc[i][j] += av[i] * bv[j];
    }
#pragma unroll
    for (int i = 0; i < 4; ++i)
#pragma unroll
      for (int j = 0; j < 4; ++j) {
        int t = t0 + i, jj = j0 + j;
        Am[t][jj] = (jj < t) ? b_l[t] * expf(c_l[t] - c_l[jj]) * acc[i][j] : 0.f;
      }
  }
  __syncthreads();

  if (tid < 64) {
    const int c = tid;
    Mm[0][c] = (c == 0) ? 1.f : 0.f;
    for (int t = 1; t < 64; ++t) {
      float a = (c == t) ? 1.f : 0.f;
      for (int j = 0; j < t; ++j) a -= Am[t][j] * Mm[j][c];
      Mm[t][c] = a;
    }
  }
  __syncthreads();

  float* Vsm = UB;
#pragma unroll
  for (int i = 0; i < 8; ++i) {
    int w = (i * 256 + tid) * 4;
    int j = w >> 7, cc = w & 127;
    float4 v = *(const float4*)&conv[(size_t)(t_base + j) * CONV_DIM + 1024 + h * 128 + cc];
    float bj = b_l[j];
    v.x *= bj; v.y *= bj; v.z *= bj; v.w *= bj;
    *(float4*)&Vsm[j * 132 + cc] = v;
  }
  __syncthreads();

  const size_t cb = (size_t)h * NC + ch;
  {
    const int t0 = (tid >> 4) * 4, c0 = (tid & 15) * 8;
    float acc[4][8] = {};
    for (int j = 0; j < 64; ++j) {
      float m[4];
#pragma unroll
      for (int i = 0; i < 4; ++i) m[i] = Mm[t0 + i][j];
      float4 va = *(const float4*)&Vsm[j * 132 + c0];
      float4 vb = *(const float4*)&Vsm[j * 132 + c0 + 4];
      float v[8] = {va.x, va.y, va.z, va.w, vb.x, vb.y, vb.z, vb.w};
#pragma unroll
      for (int i = 0; i < 4; ++i)
#pragma unroll
        for (int c = 0; c < 8; ++c) acc[i][c] += m[i] * v[c];
    }
#pragma unroll
    for (int i = 0; i < 4; ++i) {
      float4 o0 = {acc[i][0], acc[i][1], acc[i][2], acc[i][3]};
      float4 o1 = {acc[i][4], acc[i][5], acc[i][6], acc[i][7]};
      *(float4*)&Upre[cb * 8192 + (size_t)(t0 + i) * 128 + c0] = o0;
      *(float4*)&Upre[cb * 8192 + (size_t)(t0 + i) * 128 + c0 + 4] = o1;
    }
  }
  {
    const int r0 = (tid >> 3) * 4, t0 = (tid & 7) * 8;
    float acc[4][8] = {};
    for (int j = 0; j < 64; ++j) {
      float s = sW[j];
      float kk[4];
#pragma unroll
      for (int i = 0; i < 4; ++i) kk[i] = KT[r0 + i][j] * s;
      float m[8];
#pragma unroll
      for (int t = 0; t < 8; ++t) m[t] = Mm[t0 + t][j];
#pragma unroll
      for (int i = 0; i < 4; ++i)
#pragma unroll
        for (int t = 0; t < 8; ++t) acc[i][t] += kk[i] * m[t];
    }
#pragma unroll
    for (int i = 0; i < 4; ++i) {
      float4 o0 = {acc[i][0], acc[i][1], acc[i][2], acc[i][3]};
      float4 o1 = {acc[i][4], acc[i][5], acc[i][6], acc[i][7]};
      *(float4*)&WpT[cb * 8192 + (size_t)(r0 + i) * 64 + t0] = o0;
      *(float4*)&WpT[cb * 8192 + (size_t)(r0 + i) * 64 + t0 + 4] = o1;
    }
  }
  __syncthreads();

  float* QT = UB;
#pragma unroll
  for (int i = 0; i < 8; ++i) {
    int w = (i * 256 + tid) * 4;
    int tt = w >> 7, r = w & 127;
    float4 v = *(const float4*)&qn[(size_t)(t_base + tt) * 1024 + h * 128 + r];
    QT[(r + 0) * 68 + tt] = v.x; QT[(r + 1) * 68 + tt] = v.y;
    QT[(r + 2) * 68 + tt] = v.z; QT[(r + 3) * 68 + tt] = v.w;
  }
  __syncthreads();

  {
    const int t0 = (tid >> 4) * 4, j0 = (tid & 15) * 4;
    float acc[4][4] = {};
    for (int r = 0; r < 128; ++r) {
      float4 a = *(const float4*)&QT[r * 68 + t0];
      float4 b = *(const float4*)&KT[r][j0];
      float av[4] = {a.x, a.y, a.z, a.w};
      float bv[4] = {b.x, b.y, b.z, b.w};
#pragma unroll
      for (int i = 0; i < 4; ++i)
#pragma unroll
        for (int j = 0; j < 4; ++j) acc[i][j] += av[i] * bv[j];
    }
#pragma unroll
    for (int i = 0; i < 4; ++i)
#pragma unroll
      for (int j = 0; j < 4; ++j) {
        int t = t0 + i, jj = j0 + j;
        BqT[cb * 4096 + (size_t)jj * 64 + t] =
            (jj <= t) ? expf(c_l[t] - c_l[jj]) * acc[i][j] : 0.f;
      }
  }
#pragma unroll
  for (int i = 0; i < 8; ++i) {
    int w = (i * 256 + tid) * 4;
    int r = w >> 6, t = w & 63;
    float4 q = *(const float4*)&QT[r * 68 + t];
    float4 s = *(const float4*)&seQ[t];
    q.x *= s.x; q.y *= s.y; q.z *= s.z; q.w *= s.w;
    *(float4*)&Qdt[cb * 8192 + w] = q;
  }
#pragma unroll
  for (int i = 0; i < 8; ++i) {
    int w = (i * 256 + tid) * 4;
    int t = w >> 7, r = w & 127;
    float s = sKd[t];
    float4 o;
    o.x = KT[r + 0][t] * s; o.y = KT[r + 1][t] * s;
    o.z = KT[r + 2][t] * s; o.w = KT[r + 3][t] * s;
    *(float4*)&Kdm[cb * 8192 + w] = o;
  }
}

// Precompute affine form: T = dC*I - Kd^T W^T  (stored [k][r]),
//                         b = Kd^T Upre        (stored [c][r]).
// grid: (mode 0..3, ch 32, h 8). mode 0/1 = T r-halves, 2/3 = b r-halves.
__global__ __launch_bounds__(256) void k_chunkT(
    const float* __restrict__ WpT, const float* __restrict__ Kdm,
    const float* __restrict__ Upre, const float* __restrict__ dec,
    float* __restrict__ Tc, float* __restrict__ bcb) {
  const int mode = blockIdx.x;
  const int ch = blockIdx.y;
  const int h = blockIdx.z;
  const int tid = threadIdx.x;
  const size_t cb = (size_t)h * NC + ch;
  const int rbase = (mode & 1) * 64;
  const bool isT = mode < 2;
  __shared__ float Ms[64 * 132];
  if (isT) {
#pragma unroll
    for (int i = 0; i < 8; ++i) {
      int idx = i * 256 + tid;
      int k = idx >> 4;
      int t0 = (idx & 15) * 4;
      float4 v = *(const float4*)&WpT[cb * 8192 + (size_t)k * 64 + t0];
      Ms[(t0 + 0) * 132 + k] = v.x;
      Ms[(t0 + 1) * 132 + k] = v.y;
      Ms[(t0 + 2) * 132 + k] = v.z;
      Ms[(t0 + 3) * 132 + k] = v.w;
    }
  } else {
#pragma unroll
    for (int i = 0; i < 8; ++i) {
      int idx = i * 256 + tid;
      int t = idx >> 5;
      int c0 = (idx & 31) * 4;
      *(float4*)&Ms[t * 132 + c0] =
          *(const float4*)&Upre[cb * 8192 + (size_t)t * 128 + c0];
    }
  }
  __syncthreads();
  const int rr = rbase + (tid >> 4) * 4;
  const int m0 = (tid & 15) * 8;
  float acc[4][8] = {};
#pragma unroll 2
  for (int t = 0; t < 64; ++t) {
    float4 kd = *(const float4*)&Kdm[cb * 8192 + (size_t)t * 128 + rr];
    float kv[4] = {kd.x, kd.y, kd.z, kd.w};
    float4 ma = *(const float4*)&Ms[t * 132 + m0];
    float4 mb = *(const float4*)&Ms[t * 132 + m0 + 4];
    float mv[8] = {ma.x, ma.y, ma.z, ma.w, mb.x, mb.y, mb.z, mb.w};
#pragma unroll
    for (int i = 0; i < 4; ++i)
#pragma unroll
      for (int j = 0; j < 8; ++j) acc[i][j] += kv[i] * mv[j];
  }
  if (isT) {
    const float dC = dec[cb];
#pragma unroll
    for (int j = 0; j < 8; ++j) {
      int k = m0 + j;
      float4 v;
      v.x = ((rr + 0) == k ? dC : 0.f) - acc[0][j];
      v.y = ((rr + 1) == k ? dC : 0.f) - acc[1][j];
      v.z = ((rr + 2) == k ? dC : 0.f) - acc[2][j];
      v.w = ((rr + 3) == k ? dC : 0.f) - acc[3][j];
      *(float4*)&Tc[cb * 16384 + (size_t)k * 128 + rr] = v;
    }
  } else {
#pragma unroll
    for (int j = 0; j < 8; ++j) {
      float4 v = {acc[0][j], acc[1][j], acc[2][j], acc[3][j]};
      *(float4*)&bcb[cb * 16384 + (size_t)(m0 + j) * 128 + rr] = v;
    }
  }
}

// Sequential scan: S' = T S + b, T resident in double-buffered LDS with
// register prefetch of next chunk's T. 128 blocks = 8h x 16cg (8 cols).
__global__ __launch_bounds__(256) void k_chunkS3(
    const float* __restrict__ Tc, const float* __restrict__ bcb,
    float* __restrict__ Sg0, float* __restrict__ Sg1) {
  const int h = blockIdx.x >> 4;
  const int cg = blockIdx.x & 15;
  const int tid = threadIdx.x;
  const int cl = tid & 7;
  const int cglob = cg * 8 + cl;
  const int r0 = (tid >> 3) * 4;
  __shared__ float Tb[2][16384];
  __shared__ float Sm[8 * 132];

  for (int i = tid; i < 8 * 132; i += 256) Sm[i] = 0.f;
  const float* Tbase = Tc + (size_t)h * NC * 16384;
#pragma unroll
  for (int i = 0; i < 16; ++i) {
    int w = (i * 256 + tid) * 4;
    *(float4*)&Tb[0][w] = *(const float4*)&Tbase[w];
  }
  float4 s = {0.f, 0.f, 0.f, 0.f};
  __syncthreads();

  float* Sgb = (h < 4) ? (Sg0 + (size_t)h * NC * 16384)
                       : (Sg1 + (size_t)(h - 4) * NC * 16384);
  int cur = 0;
  for (int ch = 0; ch < NC; ++ch) {
    // store S_start ([c][r] layout)
    *(float4*)&Sgb[(size_t)ch * 16384 + (size_t)cglob * 128 + r0] = s;
    float4 acc = *(const float4*)&bcb[((size_t)h * NC + ch) * 16384 +
                                      (size_t)cglob * 128 + r0];
    // prefetch next chunk's T into registers (independent of S)
    float4 pt[16];
    if (ch + 1 < NC) {
      const float* Tn = Tbase + (size_t)(ch + 1) * 16384;
#pragma unroll
      for (int i = 0; i < 16; ++i)
        pt[i] = *(const float4*)&Tn[(i * 256 + tid) * 4];
    }
    // y = T s + b : T from LDS (conflict-free b128 + broadcast)
    const float* Tcur = Tb[cur];
    const float* Sv = Sm + cl * 132;
#pragma unroll 8
    for (int k0 = 0; k0 < 128; k0 += 4) {
      float4 sv = *(const float4*)&Sv[k0];
      float4 t0v = *(const float4*)&Tcur[(size_t)(k0 + 0) * 128 + r0];
      float4 t1v = *(const float4*)&Tcur[(size_t)(k0 + 1) * 128 + r0];
      float4 t2v = *(const float4*)&Tcur[(size_t)(k0 + 2) * 128 + r0];
      float4 t3v = *(const float4*)&Tcur[(size_t)(k0 + 3) * 128 + r0];
      acc.x += t0v.x * sv.x + t1v.x * sv.y + t2v.x * sv.z + t3v.x * sv.w;
      acc.y += t0v.y * sv.x + t1v.y * sv.y + t2v.y * sv.z + t3v.y * sv.w;
      acc.z += t0v.z * sv.x + t1v.z * sv.y + t2v.z * sv.z + t3v.z * sv.w;
      acc.w += t0v.w * sv.x + t1v.w * sv.y + t2v.w * sv.z + t3v.w * sv.w;
    }
    __syncthreads();
    // publish new state + write prefetched T to other buffer
    *(float4*)&Sm[cl * 132 + r0] = acc;
    if (ch + 1 < NC) {
#pragma unroll
      for (int i = 0; i < 16; ++i)
        *(float4*)&Tb[cur ^ 1][(i * 256 + tid) * 4] = pt[i];
    }
    s = acc;
    __syncthreads();
    cur ^= 1;
  }
}

// Parallel output kernel: grid (cg 8, ch 32, h 8).
// u = Upre - W^T S_start; O = Qd^T S_start + Bq^T u.
__global__ __launch_bounds__(256) void k_chunkO(
    const float* __restrict__ Upre, const float* __restrict__ WpT,
    const float* __restrict__ Qdt, const float* __restrict__ BqT,
    const float* __restrict__ Sg0, const float* __restrict__ Sg1,
    float* __restrict__ core) {
  const int cg = blockIdx.x;
  const int ch = blockIdx.y;
  const int h = blockIdx.z;
  const int cbase = cg * 16;
  const int tid = threadIdx.x;

  __shared__ float Sm[128][20];
  __shared__ float um[64][20];
  __shared__ float buf[128 * 68];
  __shared__ float Bs[64][68];

  const size_t cb = (size_t)h * NC + ch;
  const float* Up = Upre + cb * 8192;
  const float* Sc = ((h < 4) ? (Sg0 + (size_t)h * NC * 16384)
                             : (Sg1 + (size_t)(h - 4) * NC * 16384))
                    + (size_t)ch * 16384;

  {
    int c = tid & 15;
    int rr = (tid >> 4) * 8;
    float4 v0 = *(const float4*)&Sc[(size_t)(cbase + c) * 128 + rr];
    float4 v1 = *(const float4*)&Sc[(size_t)(cbase + c) * 128 + rr + 4];
    Sm[rr + 0][c] = v0.x; Sm[rr + 1][c] = v0.y;
    Sm[rr + 2][c] = v0.z; Sm[rr + 3][c] = v0.w;
    Sm[rr + 4][c] = v1.x; Sm[rr + 5][c] = v1.y;
    Sm[rr + 6][c] = v1.z; Sm[rr + 7][c] = v1.w;
  }
  {
    const float* Wp = WpT + cb * 8192;
    const float* Bp = BqT + cb * 4096;
#pragma unroll
    for (int i = 0; i < 8; ++i) {
      int w = (i * 256 + tid) * 4;
      *(float4*)&buf[(w >> 6) * 68 + (w & 63)] = *(const float4*)&Wp[w];
    }
#pragma unroll
    for (int i = 0; i < 4; ++i) {
      int w = (i * 256 + tid) * 4;
      *(float4*)&Bs[w >> 6][w & 63] = *(const float4*)&Bp[w];
    }
  }
  __syncthreads();

  const int t0 = (tid >> 3) * 2;
  const int cc = (tid & 7) * 2;

  {
    float a00 = 0, a01 = 0, a10 = 0, a11 = 0;
#pragma unroll 4
    for (int r = 0; r < 128; ++r) {
      float2 wv = *(const float2*)&buf[r * 68 + t0];
      float2 sv = *(const float2*)&Sm[r][cc];
      a00 += wv.x * sv.x; a01 += wv.x * sv.y;
      a10 += wv.y * sv.x; a11 += wv.y * sv.y;
    }
    float2 u0 = *(const float2*)&Up[(size_t)t0 * 128 + cbase + cc];
    float2 u1 = *(const float2*)&Up[(size_t)(t0 + 1) * 128 + cbase + cc];
    u0.x -= a00; u0.y -= a01;
    u1.x -= a10; u1.y -= a11;
    *(float2*)&um[t0][cc] = u0;
    *(float2*)&um[t0 + 1][cc] = u1;
  }
  __syncthreads();

  {
    const float* Qp = Qdt + cb * 8192;
#pragma unroll
    for (int i = 0; i < 8; ++i) {
      int w = (i * 256 + tid) * 4;
      *(float4*)&buf[(w >> 6) * 68 + (w & 63)] = *(const float4*)&Qp[w];
    }
  }
  __syncthreads();

  {
    float a00 = 0, a01 = 0, a10 = 0, a11 = 0;
#pragma unroll 4
    for (int r = 0; r < 128; ++r) {
      float2 qv = *(const float2*)&buf[r * 68 + t0];
      float2 sv = *(const float2*)&Sm[r][cc];
      a00 += qv.x * sv.x; a01 += qv.x * sv.y;
      a10 += qv.y * sv.x; a11 += qv.y * sv.y;
    }
#pragma unroll 4
    for (int j = 0; j < 64; ++j) {
      float2 bv = *(const float2*)&Bs[j][t0];
      float2 uv = *(const float2*)&um[j][cc];
      a00 += bv.x * uv.x; a01 += bv.x * uv.y;
      a10 += bv.y * uv.x; a11 += bv.y * uv.y;
    }
    float2 o0 = {a00, a01}, o1 = {a10, a11};
    *(float2*)&core[(size_t)(ch * 64 + t0) * 1024 + h * 128 + cbase + cc] = o0;
    *(float2*)&core[(size_t)(ch * 64 + t0 + 1) * 1024 + h * 128 + cbase + cc] = o1;
  }
}

// ---------------- gated RMSNorm per value head * silu(z); in-place safe (f32)
__global__ __launch_bounds__(256) void k_gatenorm(const float* __restrict__ core,
                                                  const float* __restrict__ qkvz,
                                                  const float* __restrict__ gnw,
                                                  float* __restrict__ y) {
  const int t = blockIdx.x, tid = threadIdx.x;
  const int wave = tid >> 6, lane = tid & 63;
  const int h = blockIdx.y * 4 + wave;
  const float* cbp = core + (size_t)t * 1024 + h * DV;
  float c0 = cbp[lane], c1 = cbp[lane + 64];
  float ss = c0 * c0 + c1 * c1;
  for (int m = 1; m < 64; m <<= 1) ss += __shfl_xor(ss, m);
  float scale = 1.f / sqrtf(ss * (1.0f / DV) + EPS);
  const float* zb = qkvz + (size_t)t * QKVZ_N + 2 * KEY_DIM + VAL_DIM + h * DV;
  float z0 = zb[lane], z1 = zb[lane + 64];
  float g0 = gnw[lane], g1 = gnw[lane + 64];
  float o0 = c0 * scale * g0 * (z0 / (1.f + expf(-z0)));
  float o1 = c1 * scale * g1 * (z1 / (1.f + expf(-z1)));
  float* yb = y + (size_t)t * 1024 + h * DV;
  yb[lane] = o0; yb[lane + 64] = o1;
}

// ---------------- router
__global__ __launch_bounds__(256) void k_router(const float* __restrict__ x2,
                                                const float* __restrict__ Wr,
                                                float* __restrict__ rinfo,
                                                int* __restrict__ cnt,
                                                float* __restrict__ outTopi) {
  const int t = blockIdx.x, tid = threadIdx.x;
  const int n = tid >> 5, kl = tid & 31;
  const float* xr = x2 + (size_t)t * HID;
  float s = 0.f;
  for (int k = kl; k < HID; k += 32) s += xr[k] * Wr[k * 8 + n];
  for (int m = 1; m < 32; m <<= 1) s += __shfl_xor(s, m);
  __shared__ float lg[8];
  if (kl == 0) lg[n] = s;
  __syncthreads();
  if (tid == 0) {
    int i0 = 0; float m0 = lg[0];
    for (int e = 1; e < 8; ++e) if (lg[e] > m0) { m0 = lg[e]; i0 = e; }
    int i1 = -1; float m1 = -1e30f;
    for (int e = 0; e < 8; ++e) if (e != i0 && lg[e] > m1) { m1 = lg[e]; i1 = e; }
    float e1 = expf(m1 - m0);
    float w0 = 1.f / (1.f + e1);
    float w1 = e1 / (1.f + e1);
    rinfo[t * 4 + 0] = (float)i0; rinfo[t * 4 + 1] = (float)i1;
    rinfo[t * 4 + 2] = w0;        rinfo[t * 4 + 3] = w1;
    atomicAdd(&cnt[i0], 1);
    atomicAdd(&cnt[i1], 1);
    outTopi[t * 2 + 0] = (float)i0;
    outTopi[t * 2 + 1] = (float)i1;
  }
}

__global__ void k_offsets(const int* __restrict__ cnt, int* __restrict__ offs,
                          int* __restrict__ cnt2) {
  if (threadIdx.x == 0) {
    int a = 0;
    for (int e = 0; e < 8; ++e) { offs[e] = a; a += cnt[e]; cnt2[e] = 0; }
  }
}

__global__ __launch_bounds__(256) void k_scatter(const float* __restrict__ rinfo,
                                                 const int* __restrict__ offs,
                                                 int* __restrict__ cnt2,
                                                 int* __restrict__ pairTok,
                                                 int* __restrict__ tokPos) {
  int t = blockIdx.x * 256 + threadIdx.x;
  if (t >= S) return;
  int i0 = (int)rinfo[t * 4 + 0], i1 = (int)rinfo[t * 4 + 1];
  int p0 = offs[i0] + atomicAdd(&cnt2[i0], 1);
  pairTok[p0] = t;
  int p1 = offs[i1] + atomicAdd(&cnt2[i1], 1);
  pairTok[p1] = t;
  tokPos[t * 2 + 0] = p0;
  tokPos[t * 2 + 1] = p1;
}

// ---------------- MoE stage 1 (MFMA bf16)
__global__ __launch_bounds__(256) void k_moe1m(const u16* __restrict__ x2b,
                                               const u16* __restrict__ WgT,
                                               const u16* __restrict__ WuT,
                                               const int* __restrict__ offs,
                                               const int* __restrict__ cnt,
                                               const int* __restrict__ pairTok,
                                               u16* __restrict__ act) {
  const int e = blockIdx.z;
  const int count = cnt[e];
  const int m0 = blockIdx.y * 128;
  if (m0 >= count) return;
  const int base = offs[e];
  __shared__ u16 Abuf[4096], Gbuf[4096], Ubuf[4096];
  const int tid = threadIdx.x;
  const int lane = tid & 63, wave = tid >> 6;
  const int wm = wave >> 1, wn = wave & 1;
  const int n0 = blockIdx.x * 128;
  const int wb0 = wave * 512, wb1 = 2048 + wave * 512;
  const int r0 = tid >> 2;
  int mr0 = m0 + r0;       if (mr0 > count - 1) mr0 = count - 1;
  int mr1 = m0 + r0 + 64;  if (mr1 > count - 1) mr1 = count - 1;
  const int t0tok = pairTok[base + mr0];
  const int t1tok = pairTok[base + mr1];
  const u16* Ag0 = x2b + (size_t)t0tok * 1024 + (tid & 3) * 8;
  const u16* Ag1 = x2b + (size_t)t1tok * 1024 + (tid & 3) * 8;
  const u16* Gg0 = WgT + (size_t)e * 512 * 1024 + (size_t)(n0 + r0) * 1024 + (tid & 3) * 8;
  const u16* Gg1 = Gg0 + (size_t)64 * 1024;
  const u16* Ug0 = WuT + (size_t)e * 512 * 1024 + (size_t)(n0 + r0) * 1024 + (tid & 3) * 8;
  const u16* Ug1 = Ug0 + (size_t)64 * 1024;
  f32x4 ag[4][4] = {}, au[4][4] = {};
  const int fr = lane & 15, kg = lane >> 4;
  for (int k0 = 0; k0 < 1024; k0 += 32) {
    gload16(Ag0 + k0, Abuf + wb0);
    gload16(Ag1 + k0, Abuf + wb1);
    gload16(Gg0 + k0, Gbuf + wb0);
    gload16(Gg1 + k0, Gbuf + wb1);
    gload16(Ug0 + k0, Ubuf + wb0);
    gload16(Ug1 + k0, Ubuf + wb1);
    __syncthreads();
    bf16x8 af[4], gf[4], uf[4];
#pragma unroll
    for (int i = 0; i < 4; ++i) {
      af[i] = *(const bf16x8*)&Abuf[(wm * 64 + i * 16 + fr) * 32 + kg * 8];
      gf[i] = *(const bf16x8*)&Gbuf[(wn * 64 + i * 16 + fr) * 32 + kg * 8];
      uf[i] = *(const bf16x8*)&Ubuf[(wn * 64 + i * 16 + fr) * 32 + kg * 8];
    }
#pragma unroll
    for (int i = 0; i < 4; ++i)
#pragma unroll
      for (int j = 0; j < 4; ++j) {
        ag[i][j] = __builtin_amdgcn_mfma_f32_16x16x32_bf16(af[i], gf[j], ag[i][j], 0, 0, 0);
        au[i][j] = __builtin_amdgcn_mfma_f32_16x16x32_bf16(af[i], uf[j], au[i][j], 0, 0, 0);
      }
    __syncthreads();
  }
#pragma unroll
  for (int i = 0; i < 4; ++i) {
#pragma unroll
    for (int j = 0; j < 4; ++j) {
      int rowt = wm * 64 + i * 16 + kg * 4;
      int col = n0 + wn * 64 + j * 16 + fr;
#pragma unroll
      for (int r = 0; r < 4; ++r) {
        if (m0 + rowt + r < count) {
          float g = ag[i][j][r], u = au[i][j][r];
          act[(size_t)(base + m0 + rowt + r) * 512 + col] =
              f2b(g / (1.f + expf(-g)) * u);
        }
      }
    }
  }
}

// ---------------- MoE stage 2 (MFMA bf16): eo = act @ Wd[e]
__global__ __launch_bounds__(256) void k_moe2m(const u16* __restrict__ act,
                                               const u16* __restrict__ WdT,
                                               const int* __restrict__ offs,
                                               const int* __restrict__ cnt,
                                               float* __restrict__ eo) {
  const int e = blockIdx.z;
  const int count = cnt[e];
  const int m0 = blockIdx.y * 128;
  if (m0 >= count) return;
  const int base = offs[e];
  __shared__ u16 Abuf[4096], Bbuf[4096];
  const int tid = threadIdx.x;
  const int lane = tid & 63, wave = tid >> 6;
  const int wm = wave >> 1, wn = wave & 1;
  const int n0 = blockIdx.x * 128;
  const int wb0 = wave * 512, wb1 = 2048 + wave * 512;
  const int r0 = tid >> 2;
  int mr0 = m0 + r0;       if (mr0 > count - 1) mr0 = count - 1;
  int mr1 = m0 + r0 + 64;  if (mr1 > count - 1) mr1 = count - 1;
  const u16* Ag0 = act + (size_t)(base + mr0) * 512 + (tid & 3) * 8;
  const u16* Ag1 = act + (size_t)(base + mr1) * 512 + (tid & 3) * 8;
  const u16* Bg0 = WdT + (size_t)e * 1024 * 512 + (size_t)(n0 + r0) * 512 + (tid & 3) * 8;
  const u16* Bg1 = Bg0 + (size_t)64 * 512;
  f32x4 acc[4][4] = {};
  const int fr = lane & 15, kg = lane >> 4;
  for (int k0 = 0; k0 < 512; k0 += 32) {
    gload16(Ag0 + k0, Abuf + wb0);
    gload16(Ag1 + k0, Abuf + wb1);
    gload16(Bg0 + k0, Bbuf + wb0);
    gload16(Bg1 + k0, Bbuf + wb1);
    __syncthreads();
    bf16x8 af[4], bfr[4];
#pragma unroll
    for (int i = 0; i < 4; ++i) {
      af[i]  = *(const bf16x8*)&Abuf[(wm * 64 + i * 16 + fr) * 32 + kg * 8];
      bfr[i] = *(const bf16x8*)&Bbuf[(wn * 64 + i * 16 + fr) * 32 + kg * 8];
    }
#pragma unroll
    for (int i = 0; i < 4; ++i)
#pragma unroll
      for (int j = 0; j < 4; ++j)
        acc[i][j] = __builtin_amdgcn_mfma_f32_16x16x32_bf16(af[i], bfr[j], acc[i][j], 0, 0, 0);
    __syncthreads();
  }
#pragma unroll
  for (int i = 0; i < 4; ++i) {
#pragma unroll
    for (int j = 0; j < 4; ++j) {
      int rowt = wm * 64 + i * 16 + kg * 4;
      int col = n0 + wn * 64 + j * 16 + fr;
#pragma unroll
      for (int r = 0; r < 4; ++r) {
        if (m0 + rowt + r < count)
          eo[(size_t)(base + m0 + rowt + r) * 1024 + col] = acc[i][j][r];
      }
    }
  }
}

// ---------------- final: out[t] += w0*eo[p0] + w1*eo[p1]
__global__ __launch_bounds__(256) void k_finish(const float* __restrict__ eo,
                                                const int* __restrict__ tokPos,
                                                const float* __restrict__ rinfo,
                                                float* __restrict__ out) {
  const int t = blockIdx.x;
  const int c = threadIdx.x * 4;
  float w0 = rinfo[t * 4 + 2], w1 = rinfo[t * 4 + 3];
  int p0 = tokPos[t * 2 + 0], p1 = tokPos[t * 2 + 1];
  float4 a = *(const float4*)&eo[(size_t)p0 * 1024 + c];
  float4 b = *(const float4*)&eo[(size_t)p1 * 1024 + c];
  float4 o = *(const float4*)&out[(size_t)t * 1024 + c];
  o.x += w0 * a.x + w1 * b.x;
  o.y += w0 * a.y + w1 * b.y;
  o.z += w0 * a.z + w1 * b.z;
  o.w += w0 * a.w + w1 * b.w;
  *(float4*)&out[(size_t)t * 1024 + c] = o;
}

extern "C" void kernel_launch(void* const* d_in, const int* in_sizes, int n_in,
                              void* d_out, int out_size, void* d_ws, size_t ws_size,
                              hipStream_t stream) {
  const float* hid      = (const float*)d_in[0];
  const float* w_ln1    = (const float*)d_in[1];
  const float* w_ln2    = (const float*)d_in[2];
  const float* W_qkvz   = (const float*)d_in[3];
  const float* W_ba     = (const float*)d_in[4];
  const float* conv_w   = (const float*)d_in[5];
  const float* dt_bias  = (const float*)d_in[6];
  const float* A_log    = (const float*)d_in[7];
  const float* gnw      = (const float*)d_in[8];
  const float* W_out    = (const float*)d_in[9];
  const float* W_router = (const float*)d_in[10];
  const float* W_gate   = (const float*)d_in[11];
  const float* W_up     = (const float*)d_in[12];
  const float* W_down   = (const float*)d_in[13];

  float* ws = (float*)d_ws;
  const size_t M1 = (size_t)1024 * 1024;
  float* x1    = ws;               // 2M (Sg0 during scan)
  float* qkvz  = x1 + 2 * M1;      // 6M
  float* conv  = qkvz + 6 * M1;    // 4M (Tc during scan; WgT/WuT after)
  float* qn    = conv + 4 * M1;    // 2M ┐ bc (4M contiguous)
  float* kn    = qn + 2 * M1;      // 2M ┘ (WdT after scan)
  float* core  = kn + 2 * M1;      // 2M
  float* Upre  = core + 2 * M1;    // 2M
  float* WpT   = Upre + 2 * M1;    // 2M
  float* Qdt   = WpT + 2 * M1;     // 2M
  float* Kdm   = Qdt + 2 * M1;     // 2M (act after scan)
  float* BqT   = Kdm + 2 * M1;     // 1M
  float* Sg1   = BqT + M1;         // 2M (heads 4-7 S_start)
  float* dec   = Sg1 + 2 * M1;     // 256
  float* ba    = dec + 256;        // 32768
  float* gb    = ba + 32768;       // 16384
  float* betab = gb + 16384;       // 16384
  float* rinfo = betab + 16384;    // 8192
  int*   ints  = (int*)(rinfo + 8192);
  int* cnt     = ints;             // 8
  int* cnt2    = ints + 8;         // 8
  int* offs    = ints + 16;        // 8
  int* pairTok = ints + 32;        // 4096
  int* tokPos  = ints + 4128;      // 4096
  u16* x1b     = (u16*)(ints + 8224);  // 2M u16

  float* Tc  = conv;               // 4M (after chunkA, before transposes)
  float* bcb = qn;                 // 4M (spans qn+kn)
  float* Sg0 = x1;                 // 2M (heads 0-3)
  u16* WgT = (u16*)conv;           // after chunkS3
  u16* WuT = (u16*)(conv + 2 * M1);
  u16* WdT = (u16*)kn;
  u16* act = (u16*)Kdm;            // after chunkT
  float* eo = Upre;                // 4M spans Upre+WpT

  float* outF = (float*)d_out;
  const size_t N1 = (size_t)S * HID;

  hipMemsetAsync(cnt, 0, 16 * sizeof(int), stream);

  k_rms<<<S, 256, 0, stream>>>(hid, w_ln1, x1, x1b);
  k_sgemm2<<<dim3(24, 16), 256, 0, stream>>>(x1, W_qkvz, nullptr, qkvz, S, QKVZ_N, HID);
  k_ba<<<S, 256, 0, stream>>>(x1, W_ba, ba);
  k_bg<<<(S * HV + 255) / 256, 256, 0, stream>>>(ba, dt_bias, A_log, gb, betab);
  k_conv<<<(S * CONV_DIM) / 256, 256, 0, stream>>>(qkvz, conv_w, conv);
  k_prep<<<S, 512, 0, stream>>>(conv, qn, kn);
  k_chunkA<<<HV * NC, 256, 0, stream>>>(qn, kn, conv, gb, betab,
                                        Upre, WpT, Qdt, Kdm, BqT, dec);
  // conv/qn/kn dead -> T-form precompute + LDS-resident sequential scan
  k_chunkT<<<dim3(4, 32, 8), 256, 0, stream>>>(WpT, Kdm, Upre, dec, Tc, bcb);
  k_chunkS3<<<128, 256, 0, stream>>>(Tc, bcb, Sg0, Sg1);
  // Tc/bc dead -> MoE bf16 weights
  k_transp<<<dim3(16, 32, 8), 256, 0, stream>>>(W_gate, WgT, 1024, 512);
  k_transp<<<dim3(16, 32, 8), 256, 0, stream>>>(W_up, WuT, 1024, 512);
  k_transp<<<dim3(32, 16, 8), 256, 0, stream>>>(W_down, WdT, 512, 1024);
  k_chunkO<<<dim3(8, 32, 8), 256, 0, stream>>>(Upre, WpT, Qdt, BqT, Sg0, Sg1, core);
  k_gatenorm<<<dim3(S, 2), 256, 0, stream>>>(core, qkvz, gnw, core);
  k_sgemm2<<<dim3(8, 16), 256, 0, stream>>>(core, W_out, hid, outF, S, HID, VAL_DIM);
  k_rms<<<S, 256, 0, stream>>>(outF, w_ln2, x1, x1b);
  k_router<<<S, 256, 0, stream>>>(x1, W_router, rinfo, cnt, outF + N1);
  k_offsets<<<1, 64, 0, stream>>>(cnt, offs, cnt2);
  k_scatter<<<(S + 255) / 256, 256, 0, stream>>>(rinfo, offs, cnt2, pairTok, tokPos);
  k_moe1m<<<dim3(4, 32, 8), 256, 0, stream>>>(x1b, WgT, WuT, offs, cnt, pairTok, act);
  k_moe2m<<<dim3(8, 32, 8), 256, 0, stream>>>(act, WdT, offs, cnt, eo);
  k_finish<<<S, 256, 0, stream>>>(eo, tokPos, rinfo, outF);
}

// Round 10
// 969.649 us; speedup vs baseline: 1.1646x; 1.0560x over previous
//
#include <hip/hip_runtime.h>

#define S 2048
#define HID 1024
#define HK 4
#define HV 8
#define DK 128
#define DV 128
#define KEY_DIM 512
#define VAL_DIM 1024
#define CONV_DIM 2048
#define QKVZ_N 3072
#define NEXP 8
#define INTER 512
#define EPS 1e-6f
#define CK 64
#define NC 32

typedef unsigned short u16;
typedef unsigned int u32;
typedef __attribute__((ext_vector_type(8))) short bf16x8;
typedef __attribute__((ext_vector_type(4))) float f32x4;

__device__ __forceinline__ u16 f2b(float f) {
  u32 u = __builtin_bit_cast(u32, f);
  u += 0x7fff + ((u >> 16) & 1);
  return (u16)(u >> 16);
}

__device__ __forceinline__ void gload16(const u16* g, u16* l) {
  __builtin_amdgcn_global_load_lds(
      (const __attribute__((address_space(1))) void*)g,
      (__attribute__((address_space(3))) void*)l, 16, 0, 0);
}

// ---------------- zero-centered RMSNorm -> f32 out + bf16 out
__global__ __launch_bounds__(256) void k_rms(const float* __restrict__ x,
                                             const float* __restrict__ w,
                                             float* __restrict__ out,
                                             u16* __restrict__ outb) {
  const int row = blockIdx.x;
  const int tid = threadIdx.x;
  const float* xr = x + (size_t)row * HID;
  float4 v = ((const float4*)xr)[tid];
  float ss = v.x*v.x + v.y*v.y + v.z*v.z + v.w*v.w;
  for (int m = 1; m < 64; m <<= 1) ss += __shfl_xor(ss, m);
  __shared__ float sred[4];
  if ((tid & 63) == 0) sred[tid >> 6] = ss;
  __syncthreads();
  float tot = sred[0] + sred[1] + sred[2] + sred[3];
  float scale = 1.0f / sqrtf(tot * (1.0f / HID) + EPS);
  float4 wv = ((const float4*)w)[tid];
  float4 o;
  o.x = v.x * scale * (1.0f + wv.x);
  o.y = v.y * scale * (1.0f + wv.y);
  o.z = v.z * scale * (1.0f + wv.z);
  o.w = v.w * scale * (1.0f + wv.w);
  ((float4*)(out + (size_t)row * HID))[tid] = o;
  u32 p0 = (u32)f2b(o.x) | ((u32)f2b(o.y) << 16);
  u32 p1 = (u32)f2b(o.z) | ((u32)f2b(o.w) << 16);
  *(uint2*)&outb[(size_t)row * HID + tid * 4] = make_uint2(p0, p1);
}

// ---------------- transpose+cast: src f32 [K][N] -> dst bf16 [N][K], batched z
__global__ __launch_bounds__(256) void k_transp(const float* __restrict__ src,
                                                u16* __restrict__ dst,
                                                int K, int N) {
  __shared__ float t[32][33];
  const size_t bo = (size_t)blockIdx.z * K * N;
  src += bo; dst += bo;
  int n0 = blockIdx.x * 32, k0 = blockIdx.y * 32;
  int tx = threadIdx.x & 31, ty = threadIdx.x >> 5;
#pragma unroll
  for (int i = 0; i < 32; i += 8)
    t[ty + i][tx] = src[(size_t)(k0 + ty + i) * N + n0 + tx];
  __syncthreads();
#pragma unroll
  for (int i = 0; i < 32; i += 8)
    dst[(size_t)(n0 + ty + i) * K + k0 + tx] = f2b(t[tx][ty + i]);
}

// ---------------- f32 GEMM 64x128 tile, 4x8/thread, conflict-free col-split
__global__ __launch_bounds__(256) void k_sgemm3(const float* __restrict__ A,
                                                const float* __restrict__ B,
                                                const float* __restrict__ Cadd,
                                                float* __restrict__ C,
                                                int M, int N, int K) {
  __shared__ float As[16][68];
  __shared__ float Bs[16][132];
  const int tid = threadIdx.x;
  const int ty = tid >> 4, tx = tid & 15;
  const int m0 = blockIdx.y * 64, n0 = blockIdx.x * 128;
  const int ar = tid >> 2, ak = (tid & 3) * 4;   // A stage: row ar, k ak..ak+3
  const int br = tid >> 4, bc = (tid & 15) * 4;  // B stage: row br, cols bc / 64+bc
  float acc[4][8] = {};
  float4 ra, rb0, rb1;
  ra  = *(const float4*)&A[(size_t)(m0 + ar) * K + ak];
  rb0 = *(const float4*)&B[(size_t)br * N + n0 + bc];
  rb1 = *(const float4*)&B[(size_t)br * N + n0 + 64 + bc];
  for (int k0 = 0; k0 < K; k0 += 16) {
    As[ak + 0][ar] = ra.x; As[ak + 1][ar] = ra.y;
    As[ak + 2][ar] = ra.z; As[ak + 3][ar] = ra.w;
    *(float4*)&Bs[br][bc] = rb0;
    *(float4*)&Bs[br][64 + bc] = rb1;
    __syncthreads();
    if (k0 + 16 < K) {
      ra  = *(const float4*)&A[(size_t)(m0 + ar) * K + k0 + 16 + ak];
      rb0 = *(const float4*)&B[(size_t)(k0 + 16 + br) * N + n0 + bc];
      rb1 = *(const float4*)&B[(size_t)(k0 + 16 + br) * N + n0 + 64 + bc];
    }
#pragma unroll
    for (int kk = 0; kk < 16; ++kk) {
      float4 av = *(const float4*)&As[kk][ty * 4];
      float4 b0 = *(const float4*)&Bs[kk][tx * 4];
      float4 b1 = *(const float4*)&Bs[kk][64 + tx * 4];
      float a[4] = {av.x, av.y, av.z, av.w};
      float b[8] = {b0.x, b0.y, b0.z, b0.w, b1.x, b1.y, b1.z, b1.w};
#pragma unroll
      for (int i = 0; i < 4; ++i)
#pragma unroll
        for (int j = 0; j < 8; ++j) acc[i][j] += a[i] * b[j];
    }
    __syncthreads();
  }
#pragma unroll
  for (int i = 0; i < 4; ++i) {
    size_t off0 = (size_t)(m0 + ty * 4 + i) * N + n0 + tx * 4;
    size_t off1 = off0 + 64;
    float4 o0 = {acc[i][0], acc[i][1], acc[i][2], acc[i][3]};
    float4 o1 = {acc[i][4], acc[i][5], acc[i][6], acc[i][7]};
    if (Cadd) {
      float4 c0 = *(const float4*)&Cadd[off0];
      float4 c1 = *(const float4*)&Cadd[off1];
      o0.x += c0.x; o0.y += c0.y; o0.z += c0.z; o0.w += c0.w;
      o1.x += c1.x; o1.y += c1.y; o1.z += c1.z; o1.w += c1.w;
    }
    *(float4*)&C[off0] = o0;
    *(float4*)&C[off1] = o1;
  }
}

// ---------------- ba = x1 @ W_ba  (N=16)
__global__ __launch_bounds__(256) void k_ba(const float* __restrict__ x1,
                                            const float* __restrict__ Wba,
                                            float* __restrict__ ba) {
  const int t = blockIdx.x, tid = threadIdx.x;
  const int n = tid >> 4, kl = tid & 15;
  const float* xr = x1 + (size_t)t * HID;
  float s = 0.f;
  for (int k = kl; k < HID; k += 16) s += xr[k] * Wba[k * 16 + n];
  for (int m = 1; m < 16; m <<= 1) s += __shfl_xor(s, m);
  if (kl == 0) ba[t * 16 + n] = s;
}

// ---------------- beta = sigmoid(b); g = -exp(A_log)*softplus(a+dt_bias)
__global__ __launch_bounds__(256) void k_bg(const float* __restrict__ ba,
                                            const float* __restrict__ dt_bias,
                                            const float* __restrict__ A_log,
                                            float* __restrict__ gb,
                                            float* __restrict__ beta) {
  int i = blockIdx.x * 256 + threadIdx.x;
  if (i >= S * HV) return;
  int t = i >> 3, h = i & 7;
  float b = ba[t * 16 + h];
  float a = ba[t * 16 + 8 + h];
  beta[i] = 1.f / (1.f + expf(-b));
  float x = a + dt_bias[h];
  float sp = fmaxf(x, 0.f) + log1pf(expf(-fabsf(x)));
  gb[i] = -expf(A_log[h]) * sp;
}

// ---------------- causal depthwise conv (K=4) + silu on qkvz cols [0,2048)
__global__ __launch_bounds__(256) void k_conv(const float* __restrict__ qkvz,
                                              const float* __restrict__ cw,
                                              float* __restrict__ conv) {
  int idx = blockIdx.x * 256 + threadIdx.x;
  int t = idx >> 11, c = idx & 2047;
  float4 w = ((const float4*)cw)[c];
  float acc = 0.f;
  if (t >= 3) {
    acc = qkvz[(size_t)(t - 3) * QKVZ_N + c] * w.x
        + qkvz[(size_t)(t - 2) * QKVZ_N + c] * w.y
        + qkvz[(size_t)(t - 1) * QKVZ_N + c] * w.z
        + qkvz[(size_t)(t    ) * QKVZ_N + c] * w.w;
  } else {
    if (t - 3 >= 0) acc += qkvz[(size_t)(t - 3) * QKVZ_N + c] * w.x;
    if (t - 2 >= 0) acc += qkvz[(size_t)(t - 2) * QKVZ_N + c] * w.y;
    if (t - 1 >= 0) acc += qkvz[(size_t)(t - 1) * QKVZ_N + c] * w.z;
    acc += qkvz[(size_t)t * QKVZ_N + c] * w.w;
  }
  conv[idx] = acc / (1.f + expf(-acc));
}

// ---------------- l2-normalize q,k per source head; repeat to 8 dest heads
__global__ __launch_bounds__(512) void k_prep(const float* __restrict__ conv,
                                              float* __restrict__ qn,
                                              float* __restrict__ kn) {
  const int t = blockIdx.x, tid = threadIdx.x;
  const int sh = tid >> 7;
  const int d = tid & 127;
  float qv = conv[(size_t)t * CONV_DIM + sh * DK + d];
  float kv = conv[(size_t)t * CONV_DIM + KEY_DIM + sh * DK + d];
  float sq = qv * qv, sk = kv * kv;
  for (int m = 1; m < 64; m <<= 1) { sq += __shfl_xor(sq, m); sk += __shfl_xor(sk, m); }
  __shared__ float rq[8], rk[8];
  const int wave = tid >> 6;
  if ((tid & 63) == 0) { rq[wave] = sq; rk[wave] = sk; }
  __syncthreads();
  float sumq = rq[sh * 2] + rq[sh * 2 + 1];
  float sumk = rk[sh * 2] + rk[sh * 2 + 1];
  float qs = (1.f / sqrtf(sumq + EPS)) * 0.08838834764831845f;
  float ks = 1.f / sqrtf(sumk + EPS);
  float qo = qv * qs, ko = kv * ks;
  size_t b0 = (size_t)t * 1024 + (size_t)(sh * 2) * DK + d;
  qn[b0] = qo; qn[b0 + DK] = qo;
  kn[b0] = ko; kn[b0 + DK] = ko;
}

// ================= chunked gated delta rule =================
__global__ __launch_bounds__(256) void k_chunkA(
    const float* __restrict__ qn, const float* __restrict__ kn,
    const float* __restrict__ conv, const float* __restrict__ gbuf,
    const float* __restrict__ betab,
    float* __restrict__ Upre, float* __restrict__ WpT,
    float* __restrict__ Qdt, float* __restrict__ Kdm,
    float* __restrict__ BqT, float* __restrict__ dec) {
  const int h = blockIdx.x >> 5;
  const int ch = blockIdx.x & 31;
  const int tid = threadIdx.x;
  const int t_base = ch * CK;

  __shared__ float KT[128][68];
  __shared__ float UB[8704];
  __shared__ float Am[64][68];
  __shared__ float Mm[64][68];
  __shared__ float c_l[64], b_l[64], sW[64], seQ[64], sKd[64];

#pragma unroll
  for (int i = 0; i < 8; ++i) {
    int w = (i * 256 + tid) * 4;
    int tt = w >> 7, r = w & 127;
    float4 v = *(const float4*)&kn[(size_t)(t_base + tt) * 1024 + h * 128 + r];
    KT[r + 0][tt] = v.x; KT[r + 1][tt] = v.y; KT[r + 2][tt] = v.z; KT[r + 3][tt] = v.w;
  }
  if (tid < 64) {
    c_l[tid] = gbuf[(t_base + tid) * HV + h];
    b_l[tid] = betab[(t_base + tid) * HV + h];
  }
  __syncthreads();
  if (tid == 0) {
    float run = 0.f;
    for (int t = 0; t < 64; ++t) { run += c_l[t]; c_l[t] = run; }
    dec[h * NC + ch] = expf(run);
  }
  __syncthreads();
  if (tid < 64) {
    sW[tid] = b_l[tid] * expf(c_l[tid]);
    seQ[tid] = expf(c_l[tid]);
    sKd[tid] = expf(c_l[63] - c_l[tid]);
  }
  __syncthreads();

  {
    const int t0 = (tid >> 4) * 4, j0 = (tid & 15) * 4;
    float acc[4][4] = {};
    for (int r = 0; r < 128; ++r) {
      float4 a = *(const float4*)&KT[r][t0];
      float4 b = *(const float4*)&KT[r][j0];
      float av[4] = {a.x, a.y, a.z, a.w};
      float bv[4] = {b.x, b.y, b.z, b.w};
#pragma unroll
      for (int i = 0; i < 4; ++i)
#pragma unroll
        for (int j = 0; j < 4; ++j) acc[i][j] += av[i] * bv[j];
    }
#pragma unroll
    for (int i = 0; i < 4; ++i)
#pragma unroll
      for (int j = 0; j < 4; ++j) {
        int t = t0 + i, jj = j0 + j;
        Am[t][jj] = (jj < t) ? b_l[t] * expf(c_l[t] - c_l[jj]) * acc[i][j] : 0.f;
      }
  }
  __syncthreads();

  if (tid < 64) {
    const int c = tid;
    Mm[0][c] = (c == 0) ? 1.f : 0.f;
    for (int t = 1; t < 64; ++t) {
      float a = (c == t) ? 1.f : 0.f;
      for (int j = 0; j < t; ++j) a -= Am[t][j] * Mm[j][c];
      Mm[t][c] = a;
    }
  }
  __syncthreads();

  float* Vsm = UB;
#pragma unroll
  for (int i = 0; i < 8; ++i) {
    int w = (i * 256 + tid) * 4;
    int j = w >> 7, cc = w & 127;
    float4 v = *(const float4*)&conv[(size_t)(t_base + j) * CONV_DIM + 1024 + h * 128 + cc];
    float bj = b_l[j];
    v.x *= bj; v.y *= bj; v.z *= bj; v.w *= bj;
    *(float4*)&Vsm[j * 132 + cc] = v;
  }
  __syncthreads();

  const size_t cb = (size_t)h * NC + ch;
  {
    const int t0 = (tid >> 4) * 4, c0 = (tid & 15) * 8;
    float acc[4][8] = {};
    for (int j = 0; j < 64; ++j) {
      float m[4];
#pragma unroll
      for (int i = 0; i < 4; ++i) m[i] = Mm[t0 + i][j];
      float4 va = *(const float4*)&Vsm[j * 132 + c0];
      float4 vb = *(const float4*)&Vsm[j * 132 + c0 + 4];
      float v[8] = {va.x, va.y, va.z, va.w, vb.x, vb.y, vb.z, vb.w};
#pragma unroll
      for (int i = 0; i < 4; ++i)
#pragma unroll
        for (int c = 0; c < 8; ++c) acc[i][c] += m[i] * v[c];
    }
#pragma unroll
    for (int i = 0; i < 4; ++i) {
      float4 o0 = {acc[i][0], acc[i][1], acc[i][2], acc[i][3]};
      float4 o1 = {acc[i][4], acc[i][5], acc[i][6], acc[i][7]};
      *(float4*)&Upre[cb * 8192 + (size_t)(t0 + i) * 128 + c0] = o0;
      *(float4*)&Upre[cb * 8192 + (size_t)(t0 + i) * 128 + c0 + 4] = o1;
    }
  }
  {
    const int r0 = (tid >> 3) * 4, t0 = (tid & 7) * 8;
    float acc[4][8] = {};
    for (int j = 0; j < 64; ++j) {
      float s = sW[j];
      float kk[4];
#pragma unroll
      for (int i = 0; i < 4; ++i) kk[i] = KT[r0 + i][j] * s;
      float m[8];
#pragma unroll
      for (int t = 0; t < 8; ++t) m[t] = Mm[t0 + t][j];
#pragma unroll
      for (int i = 0; i < 4; ++i)
#pragma unroll
        for (int t = 0; t < 8; ++t) acc[i][t] += kk[i] * m[t];
    }
#pragma unroll
    for (int i = 0; i < 4; ++i) {
      float4 o0 = {acc[i][0], acc[i][1], acc[i][2], acc[i][3]};
      float4 o1 = {acc[i][4], acc[i][5], acc[i][6], acc[i][7]};
      *(float4*)&WpT[cb * 8192 + (size_t)(r0 + i) * 64 + t0] = o0;
      *(float4*)&WpT[cb * 8192 + (size_t)(r0 + i) * 64 + t0 + 4] = o1;
    }
  }
  __syncthreads();

  float* QT = UB;
#pragma unroll
  for (int i = 0; i < 8; ++i) {
    int w = (i * 256 + tid) * 4;
    int tt = w >> 7, r = w & 127;
    float4 v = *(const float4*)&qn[(size_t)(t_base + tt) * 1024 + h * 128 + r];
    QT[(r + 0) * 68 + tt] = v.x; QT[(r + 1) * 68 + tt] = v.y;
    QT[(r + 2) * 68 + tt] = v.z; QT[(r + 3) * 68 + tt] = v.w;
  }
  __syncthreads();

  {
    const int t0 = (tid >> 4) * 4, j0 = (tid & 15) * 4;
    float acc[4][4] = {};
    for (int r = 0; r < 128; ++r) {
      float4 a = *(const float4*)&QT[r * 68 + t0];
      float4 b = *(const float4*)&KT[r][j0];
      float av[4] = {a.x, a.y, a.z, a.w};
      float bv[4] = {b.x, b.y, b.z, b.w};
#pragma unroll
      for (int i = 0; i < 4; ++i)
#pragma unroll
        for (int j = 0; j < 4; ++j) acc[i][j] += av[i] * bv[j];
    }
#pragma unroll
    for (int i = 0; i < 4; ++i)
#pragma unroll
      for (int j = 0; j < 4; ++j) {
        int t = t0 + i, jj = j0 + j;
        BqT[cb * 4096 + (size_t)jj * 64 + t] =
            (jj <= t) ? expf(c_l[t] - c_l[jj]) * acc[i][j] : 0.f;
      }
  }
#pragma unroll
  for (int i = 0; i < 8; ++i) {
    int w = (i * 256 + tid) * 4;
    int r = w >> 6, t = w & 63;
    float4 q = *(const float4*)&QT[r * 68 + t];
    float4 s = *(const float4*)&seQ[t];
    q.x *= s.x; q.y *= s.y; q.z *= s.z; q.w *= s.w;
    *(float4*)&Qdt[cb * 8192 + w] = q;
  }
#pragma unroll
  for (int i = 0; i < 8; ++i) {
    int w = (i * 256 + tid) * 4;
    int t = w >> 7, r = w & 127;
    float s = sKd[t];
    float4 o;
    o.x = KT[r + 0][t] * s; o.y = KT[r + 1][t] * s;
    o.z = KT[r + 2][t] * s; o.w = KT[r + 3][t] * s;
    *(float4*)&Kdm[cb * 8192 + w] = o;
  }
}

// Precompute affine form: T = dC*I - Kd^T W^T  (stored [k][r]),
//                         b = Kd^T Upre        (stored [c][r]).
__global__ __launch_bounds__(256) void k_chunkT(
    const float* __restrict__ WpT, const float* __restrict__ Kdm,
    const float* __restrict__ Upre, const float* __restrict__ dec,
    float* __restrict__ Tc, float* __restrict__ bcb) {
  const int mode = blockIdx.x;
  const int ch = blockIdx.y;
  const int h = blockIdx.z;
  const int tid = threadIdx.x;
  const size_t cb = (size_t)h * NC + ch;
  const int rbase = (mode & 1) * 64;
  const bool isT = mode < 2;
  __shared__ float Ms[64 * 132];
  if (isT) {
#pragma unroll
    for (int i = 0; i < 8; ++i) {
      int idx = i * 256 + tid;
      int k = idx >> 4;
      int t0 = (idx & 15) * 4;
      float4 v = *(const float4*)&WpT[cb * 8192 + (size_t)k * 64 + t0];
      Ms[(t0 + 0) * 132 + k] = v.x;
      Ms[(t0 + 1) * 132 + k] = v.y;
      Ms[(t0 + 2) * 132 + k] = v.z;
      Ms[(t0 + 3) * 132 + k] = v.w;
    }
  } else {
#pragma unroll
    for (int i = 0; i < 8; ++i) {
      int idx = i * 256 + tid;
      int t = idx >> 5;
      int c0 = (idx & 31) * 4;
      *(float4*)&Ms[t * 132 + c0] =
          *(const float4*)&Upre[cb * 8192 + (size_t)t * 128 + c0];
    }
  }
  __syncthreads();
  const int rr = rbase + (tid >> 4) * 4;
  const int m0 = (tid & 15) * 8;
  float acc[4][8] = {};
#pragma unroll 2
  for (int t = 0; t < 64; ++t) {
    float4 kd = *(const float4*)&Kdm[cb * 8192 + (size_t)t * 128 + rr];
    float kv[4] = {kd.x, kd.y, kd.z, kd.w};
    float4 ma = *(const float4*)&Ms[t * 132 + m0];
    float4 mb = *(const float4*)&Ms[t * 132 + m0 + 4];
    float mv[8] = {ma.x, ma.y, ma.z, ma.w, mb.x, mb.y, mb.z, mb.w};
#pragma unroll
    for (int i = 0; i < 4; ++i)
#pragma unroll
      for (int j = 0; j < 8; ++j) acc[i][j] += kv[i] * mv[j];
  }
  if (isT) {
    const float dC = dec[cb];
#pragma unroll
    for (int j = 0; j < 8; ++j) {
      int k = m0 + j;
      float4 v;
      v.x = ((rr + 0) == k ? dC : 0.f) - acc[0][j];
      v.y = ((rr + 1) == k ? dC : 0.f) - acc[1][j];
      v.z = ((rr + 2) == k ? dC : 0.f) - acc[2][j];
      v.w = ((rr + 3) == k ? dC : 0.f) - acc[3][j];
      *(float4*)&Tc[cb * 16384 + (size_t)k * 128 + rr] = v;
    }
  } else {
#pragma unroll
    for (int j = 0; j < 8; ++j) {
      float4 v = {acc[0][j], acc[1][j], acc[2][j], acc[3][j]};
      *(float4*)&bcb[cb * 16384 + (size_t)(m0 + j) * 128 + rr] = v;
    }
  }
}

// Sequential scan: S' = T S + b, T resident in double-buffered LDS with
// register prefetch of next chunk's T. 128 blocks = 8h x 16cg (8 cols).
__global__ __launch_bounds__(256) void k_chunkS3(
    const float* __restrict__ Tc, const float* __restrict__ bcb,
    float* __restrict__ Sg0, float* __restrict__ Sg1) {
  const int h = blockIdx.x >> 4;
  const int cg = blockIdx.x & 15;
  const int tid = threadIdx.x;
  const int cl = tid & 7;
  const int cglob = cg * 8 + cl;
  const int r0 = (tid >> 3) * 4;
  __shared__ float Tb[2][16384];
  __shared__ float Sm[8 * 132];

  for (int i = tid; i < 8 * 132; i += 256) Sm[i] = 0.f;
  const float* Tbase = Tc + (size_t)h * NC * 16384;
#pragma unroll
  for (int i = 0; i < 16; ++i) {
    int w = (i * 256 + tid) * 4;
    *(float4*)&Tb[0][w] = *(const float4*)&Tbase[w];
  }
  float4 s = {0.f, 0.f, 0.f, 0.f};
  __syncthreads();

  float* Sgb = (h < 4) ? (Sg0 + (size_t)h * NC * 16384)
                       : (Sg1 + (size_t)(h - 4) * NC * 16384);
  int cur = 0;
  for (int ch = 0; ch < NC; ++ch) {
    *(float4*)&Sgb[(size_t)ch * 16384 + (size_t)cglob * 128 + r0] = s;
    float4 acc = *(const float4*)&bcb[((size_t)h * NC + ch) * 16384 +
                                      (size_t)cglob * 128 + r0];
    float4 pt[16];
    if (ch + 1 < NC) {
      const float* Tn = Tbase + (size_t)(ch + 1) * 16384;
#pragma unroll
      for (int i = 0; i < 16; ++i)
        pt[i] = *(const float4*)&Tn[(i * 256 + tid) * 4];
    }
    const float* Tcur = Tb[cur];
    const float* Sv = Sm + cl * 132;
#pragma unroll 8
    for (int k0 = 0; k0 < 128; k0 += 4) {
      float4 sv = *(const float4*)&Sv[k0];
      float4 t0v = *(const float4*)&Tcur[(size_t)(k0 + 0) * 128 + r0];
      float4 t1v = *(const float4*)&Tcur[(size_t)(k0 + 1) * 128 + r0];
      float4 t2v = *(const float4*)&Tcur[(size_t)(k0 + 2) * 128 + r0];
      float4 t3v = *(const float4*)&Tcur[(size_t)(k0 + 3) * 128 + r0];
      acc.x += t0v.x * sv.x + t1v.x * sv.y + t2v.x * sv.z + t3v.x * sv.w;
      acc.y += t0v.y * sv.x + t1v.y * sv.y + t2v.y * sv.z + t3v.y * sv.w;
      acc.z += t0v.z * sv.x + t1v.z * sv.y + t2v.z * sv.z + t3v.z * sv.w;
      acc.w += t0v.w * sv.x + t1v.w * sv.y + t2v.w * sv.z + t3v.w * sv.w;
    }
    __syncthreads();
    *(float4*)&Sm[cl * 132 + r0] = acc;
    if (ch + 1 < NC) {
#pragma unroll
      for (int i = 0; i < 16; ++i)
        *(float4*)&Tb[cur ^ 1][(i * 256 + tid) * 4] = pt[i];
    }
    s = acc;
    __syncthreads();
    cur ^= 1;
  }
}

// Parallel output kernel: grid (cg 8, ch 32, h 8).
__global__ __launch_bounds__(256) void k_chunkO(
    const float* __restrict__ Upre, const float* __restrict__ WpT,
    const float* __restrict__ Qdt, const float* __restrict__ BqT,
    const float* __restrict__ Sg0, const float* __restrict__ Sg1,
    float* __restrict__ core) {
  const int cg = blockIdx.x;
  const int ch = blockIdx.y;
  const int h = blockIdx.z;
  const int cbase = cg * 16;
  const int tid = threadIdx.x;

  __shared__ float Sm[128][20];
  __shared__ float um[64][20];
  __shared__ float buf[128 * 68];
  __shared__ float Bs[64][68];

  const size_t cb = (size_t)h * NC + ch;
  const float* Up = Upre + cb * 8192;
  const float* Sc = ((h < 4) ? (Sg0 + (size_t)h * NC * 16384)
                             : (Sg1 + (size_t)(h - 4) * NC * 16384))
                    + (size_t)ch * 16384;

  {
    int c = tid & 15;
    int rr = (tid >> 4) * 8;
    float4 v0 = *(const float4*)&Sc[(size_t)(cbase + c) * 128 + rr];
    float4 v1 = *(const float4*)&Sc[(size_t)(cbase + c) * 128 + rr + 4];
    Sm[rr + 0][c] = v0.x; Sm[rr + 1][c] = v0.y;
    Sm[rr + 2][c] = v0.z; Sm[rr + 3][c] = v0.w;
    Sm[rr + 4][c] = v1.x; Sm[rr + 5][c] = v1.y;
    Sm[rr + 6][c] = v1.z; Sm[rr + 7][c] = v1.w;
  }
  {
    const float* Wp = WpT + cb * 8192;
    const float* Bp = BqT + cb * 4096;
#pragma unroll
    for (int i = 0; i < 8; ++i) {
      int w = (i * 256 + tid) * 4;
      *(float4*)&buf[(w >> 6) * 68 + (w & 63)] = *(const float4*)&Wp[w];
    }
#pragma unroll
    for (int i = 0; i < 4; ++i) {
      int w = (i * 256 + tid) * 4;
      *(float4*)&Bs[w >> 6][w & 63] = *(const float4*)&Bp[w];
    }
  }
  __syncthreads();

  const int t0 = (tid >> 3) * 2;
  const int cc = (tid & 7) * 2;

  {
    float a00 = 0, a01 = 0, a10 = 0, a11 = 0;
#pragma unroll 4
    for (int r = 0; r < 128; ++r) {
      float2 wv = *(const float2*)&buf[r * 68 + t0];
      float2 sv = *(const float2*)&Sm[r][cc];
      a00 += wv.x * sv.x; a01 += wv.x * sv.y;
      a10 += wv.y * sv.x; a11 += wv.y * sv.y;
    }
    float2 u0 = *(const float2*)&Up[(size_t)t0 * 128 + cbase + cc];
    float2 u1 = *(const float2*)&Up[(size_t)(t0 + 1) * 128 + cbase + cc];
    u0.x -= a00; u0.y -= a01;
    u1.x -= a10; u1.y -= a11;
    *(float2*)&um[t0][cc] = u0;
    *(float2*)&um[t0 + 1][cc] = u1;
  }
  __syncthreads();

  {
    const float* Qp = Qdt + cb * 8192;
#pragma unroll
    for (int i = 0; i < 8; ++i) {
      int w = (i * 256 + tid) * 4;
      *(float4*)&buf[(w >> 6) * 68 + (w & 63)] = *(const float4*)&Qp[w];
    }
  }
  __syncthreads();

  {
    float a00 = 0, a01 = 0, a10 = 0, a11 = 0;
#pragma unroll 4
    for (int r = 0; r < 128; ++r) {
      float2 qv = *(const float2*)&buf[r * 68 + t0];
      float2 sv = *(const float2*)&Sm[r][cc];
      a00 += qv.x * sv.x; a01 += qv.x * sv.y;
      a10 += qv.y * sv.x; a11 += qv.y * sv.y;
    }
#pragma unroll 4
    for (int j = 0; j < 64; ++j) {
      float2 bv = *(const float2*)&Bs[j][t0];
      float2 uv = *(const float2*)&um[j][cc];
      a00 += bv.x * uv.x; a01 += bv.x * uv.y;
      a10 += bv.y * uv.x; a11 += bv.y * uv.y;
    }
    float2 o0 = {a00, a01}, o1 = {a10, a11};
    *(float2*)&core[(size_t)(ch * 64 + t0) * 1024 + h * 128 + cbase + cc] = o0;
    *(float2*)&core[(size_t)(ch * 64 + t0 + 1) * 1024 + h * 128 + cbase + cc] = o1;
  }
}

// ---------------- gated RMSNorm per value head * silu(z); in-place safe (f32)
__global__ __launch_bounds__(256) void k_gatenorm(const float* __restrict__ core,
                                                  const float* __restrict__ qkvz,
                                                  const float* __restrict__ gnw,
                                                  float* __restrict__ y) {
  const int t = blockIdx.x, tid = threadIdx.x;
  const int wave = tid >> 6, lane = tid & 63;
  const int h = blockIdx.y * 4 + wave;
  const float* cbp = core + (size_t)t * 1024 + h * DV;
  float c0 = cbp[lane], c1 = cbp[lane + 64];
  float ss = c0 * c0 + c1 * c1;
  for (int m = 1; m < 64; m <<= 1) ss += __shfl_xor(ss, m);
  float scale = 1.f / sqrtf(ss * (1.0f / DV) + EPS);
  const float* zb = qkvz + (size_t)t * QKVZ_N + 2 * KEY_DIM + VAL_DIM + h * DV;
  float z0 = zb[lane], z1 = zb[lane + 64];
  float g0 = gnw[lane], g1 = gnw[lane + 64];
  float o0 = c0 * scale * g0 * (z0 / (1.f + expf(-z0)));
  float o1 = c1 * scale * g1 * (z1 / (1.f + expf(-z1)));
  float* yb = y + (size_t)t * 1024 + h * DV;
  yb[lane] = o0; yb[lane + 64] = o1;
}

// ---------------- router
__global__ __launch_bounds__(256) void k_router(const float* __restrict__ x2,
                                                const float* __restrict__ Wr,
                                                float* __restrict__ rinfo,
                                                int* __restrict__ cnt,
                                                float* __restrict__ outTopi) {
  const int t = blockIdx.x, tid = threadIdx.x;
  const int n = tid >> 5, kl = tid & 31;
  const float* xr = x2 + (size_t)t * HID;
  float s = 0.f;
  for (int k = kl; k < HID; k += 32) s += xr[k] * Wr[k * 8 + n];
  for (int m = 1; m < 32; m <<= 1) s += __shfl_xor(s, m);
  __shared__ float lg[8];
  if (kl == 0) lg[n] = s;
  __syncthreads();
  if (tid == 0) {
    int i0 = 0; float m0 = lg[0];
    for (int e = 1; e < 8; ++e) if (lg[e] > m0) { m0 = lg[e]; i0 = e; }
    int i1 = -1; float m1 = -1e30f;
    for (int e = 0; e < 8; ++e) if (e != i0 && lg[e] > m1) { m1 = lg[e]; i1 = e; }
    float e1 = expf(m1 - m0);
    float w0 = 1.f / (1.f + e1);
    float w1 = e1 / (1.f + e1);
    rinfo[t * 4 + 0] = (float)i0; rinfo[t * 4 + 1] = (float)i1;
    rinfo[t * 4 + 2] = w0;        rinfo[t * 4 + 3] = w1;
    atomicAdd(&cnt[i0], 1);
    atomicAdd(&cnt[i1], 1);
    outTopi[t * 2 + 0] = (float)i0;
    outTopi[t * 2 + 1] = (float)i1;
  }
}

__global__ void k_offsets(const int* __restrict__ cnt, int* __restrict__ offs,
                          int* __restrict__ cnt2) {
  if (threadIdx.x == 0) {
    int a = 0;
    for (int e = 0; e < 8; ++e) { offs[e] = a; a += cnt[e]; cnt2[e] = 0; }
  }
}

__global__ __launch_bounds__(256) void k_scatter(const float* __restrict__ rinfo,
                                                 const int* __restrict__ offs,
                                                 int* __restrict__ cnt2,
                                                 int* __restrict__ pairTok,
                                                 int* __restrict__ tokPos) {
  int t = blockIdx.x * 256 + threadIdx.x;
  if (t >= S) return;
  int i0 = (int)rinfo[t * 4 + 0], i1 = (int)rinfo[t * 4 + 1];
  int p0 = offs[i0] + atomicAdd(&cnt2[i0], 1);
  pairTok[p0] = t;
  int p1 = offs[i1] + atomicAdd(&cnt2[i1], 1);
  pairTok[p1] = t;
  tokPos[t * 2 + 0] = p0;
  tokPos[t * 2 + 1] = p1;
}

// ---------------- MoE stage 1 (MFMA bf16)
__global__ __launch_bounds__(256) void k_moe1m(const u16* __restrict__ x2b,
                                               const u16* __restrict__ WgT,
                                               const u16* __restrict__ WuT,
                                               const int* __restrict__ offs,
                                               const int* __restrict__ cnt,
                                               const int* __restrict__ pairTok,
                                               u16* __restrict__ act) {
  const int e = blockIdx.z;
  const int count = cnt[e];
  const int m0 = blockIdx.y * 128;
  if (m0 >= count) return;
  const int base = offs[e];
  __shared__ u16 Abuf[4096], Gbuf[4096], Ubuf[4096];
  const int tid = threadIdx.x;
  const int lane = tid & 63, wave = tid >> 6;
  const int wm = wave >> 1, wn = wave & 1;
  const int n0 = blockIdx.x * 128;
  const int wb0 = wave * 512, wb1 = 2048 + wave * 512;
  const int r0 = tid >> 2;
  int mr0 = m0 + r0;       if (mr0 > count - 1) mr0 = count - 1;
  int mr1 = m0 + r0 + 64;  if (mr1 > count - 1) mr1 = count - 1;
  const int t0tok = pairTok[base + mr0];
  const int t1tok = pairTok[base + mr1];
  const u16* Ag0 = x2b + (size_t)t0tok * 1024 + (tid & 3) * 8;
  const u16* Ag1 = x2b + (size_t)t1tok * 1024 + (tid & 3) * 8;
  const u16* Gg0 = WgT + (size_t)e * 512 * 1024 + (size_t)(n0 + r0) * 1024 + (tid & 3) * 8;
  const u16* Gg1 = Gg0 + (size_t)64 * 1024;
  const u16* Ug0 = WuT + (size_t)e * 512 * 1024 + (size_t)(n0 + r0) * 1024 + (tid & 3) * 8;
  const u16* Ug1 = Ug0 + (size_t)64 * 1024;
  f32x4 ag[4][4] = {}, au[4][4] = {};
  const int fr = lane & 15, kg = lane >> 4;
  for (int k0 = 0; k0 < 1024; k0 += 32) {
    gload16(Ag0 + k0, Abuf + wb0);
    gload16(Ag1 + k0, Abuf + wb1);
    gload16(Gg0 + k0, Gbuf + wb0);
    gload16(Gg1 + k0, Gbuf + wb1);
    gload16(Ug0 + k0, Ubuf + wb0);
    gload16(Ug1 + k0, Ubuf + wb1);
    __syncthreads();
    bf16x8 af[4], gf[4], uf[4];
#pragma unroll
    for (int i = 0; i < 4; ++i) {
      af[i] = *(const bf16x8*)&Abuf[(wm * 64 + i * 16 + fr) * 32 + kg * 8];
      gf[i] = *(const bf16x8*)&Gbuf[(wn * 64 + i * 16 + fr) * 32 + kg * 8];
      uf[i] = *(const bf16x8*)&Ubuf[(wn * 64 + i * 16 + fr) * 32 + kg * 8];
    }
#pragma unroll
    for (int i = 0; i < 4; ++i)
#pragma unroll
      for (int j = 0; j < 4; ++j) {
        ag[i][j] = __builtin_amdgcn_mfma_f32_16x16x32_bf16(af[i], gf[j], ag[i][j], 0, 0, 0);
        au[i][j] = __builtin_amdgcn_mfma_f32_16x16x32_bf16(af[i], uf[j], au[i][j], 0, 0, 0);
      }
    __syncthreads();
  }
#pragma unroll
  for (int i = 0; i < 4; ++i) {
#pragma unroll
    for (int j = 0; j < 4; ++j) {
      int rowt = wm * 64 + i * 16 + kg * 4;
      int col = n0 + wn * 64 + j * 16 + fr;
#pragma unroll
      for (int r = 0; r < 4; ++r) {
        if (m0 + rowt + r < count) {
          float g = ag[i][j][r], u = au[i][j][r];
          act[(size_t)(base + m0 + rowt + r) * 512 + col] =
              f2b(g / (1.f + expf(-g)) * u);
        }
      }
    }
  }
}

// ---------------- MoE stage 2 (MFMA bf16): eo = act @ Wd[e]
__global__ __launch_bounds__(256) void k_moe2m(const u16* __restrict__ act,
                                               const u16* __restrict__ WdT,
                                               const int* __restrict__ offs,
                                               const int* __restrict__ cnt,
                                               float* __restrict__ eo) {
  const int e = blockIdx.z;
  const int count = cnt[e];
  const int m0 = blockIdx.y * 128;
  if (m0 >= count) return;
  const int base = offs[e];
  __shared__ u16 Abuf[4096], Bbuf[4096];
  const int tid = threadIdx.x;
  const int lane = tid & 63, wave = tid >> 6;
  const int wm = wave >> 1, wn = wave & 1;
  const int n0 = blockIdx.x * 128;
  const int wb0 = wave * 512, wb1 = 2048 + wave * 512;
  const int r0 = tid >> 2;
  int mr0 = m0 + r0;       if (mr0 > count - 1) mr0 = count - 1;
  int mr1 = m0 + r0 + 64;  if (mr1 > count - 1) mr1 = count - 1;
  const u16* Ag0 = act + (size_t)(base + mr0) * 512 + (tid & 3) * 8;
  const u16* Ag1 = act + (size_t)(base + mr1) * 512 + (tid & 3) * 8;
  const u16* Bg0 = WdT + (size_t)e * 1024 * 512 + (size_t)(n0 + r0) * 512 + (tid & 3) * 8;
  const u16* Bg1 = Bg0 + (size_t)64 * 512;
  f32x4 acc[4][4] = {};
  const int fr = lane & 15, kg = lane >> 4;
  for (int k0 = 0; k0 < 512; k0 += 32) {
    gload16(Ag0 + k0, Abuf + wb0);
    gload16(Ag1 + k0, Abuf + wb1);
    gload16(Bg0 + k0, Bbuf + wb0);
    gload16(Bg1 + k0, Bbuf + wb1);
    __syncthreads();
    bf16x8 af[4], bfr[4];
#pragma unroll
    for (int i = 0; i < 4; ++i) {
      af[i]  = *(const bf16x8*)&Abuf[(wm * 64 + i * 16 + fr) * 32 + kg * 8];
      bfr[i] = *(const bf16x8*)&Bbuf[(wn * 64 + i * 16 + fr) * 32 + kg * 8];
    }
#pragma unroll
    for (int i = 0; i < 4; ++i)
#pragma unroll
      for (int j = 0; j < 4; ++j)
        acc[i][j] = __builtin_amdgcn_mfma_f32_16x16x32_bf16(af[i], bfr[j], acc[i][j], 0, 0, 0);
    __syncthreads();
  }
#pragma unroll
  for (int i = 0; i < 4; ++i) {
#pragma unroll
    for (int j = 0; j < 4; ++j) {
      int rowt = wm * 64 + i * 16 + kg * 4;
      int col = n0 + wn * 64 + j * 16 + fr;
#pragma unroll
      for (int r = 0; r < 4; ++r) {
        if (m0 + rowt + r < count)
          eo[(size_t)(base + m0 + rowt + r) * 1024 + col] = acc[i][j][r];
      }
    }
  }
}

// ---------------- final: out[t] += w0*eo[p0] + w1*eo[p1]
__global__ __launch_bounds__(256) void k_finish(const float* __restrict__ eo,
                                                const int* __restrict__ tokPos,
                                                const float* __restrict__ rinfo,
                                                float* __restrict__ out) {
  const int t = blockIdx.x;
  const int c = threadIdx.x * 4;
  float w0 = rinfo[t * 4 + 2], w1 = rinfo[t * 4 + 3];
  int p0 = tokPos[t * 2 + 0], p1 = tokPos[t * 2 + 1];
  float4 a = *(const float4*)&eo[(size_t)p0 * 1024 + c];
  float4 b = *(const float4*)&eo[(size_t)p1 * 1024 + c];
  float4 o = *(const float4*)&out[(size_t)t * 1024 + c];
  o.x += w0 * a.x + w1 * b.x;
  o.y += w0 * a.y + w1 * b.y;
  o.z += w0 * a.z + w1 * b.z;
  o.w += w0 * a.w + w1 * b.w;
  *(float4*)&out[(size_t)t * 1024 + c] = o;
}

extern "C" void kernel_launch(void* const* d_in, const int* in_sizes, int n_in,
                              void* d_out, int out_size, void* d_ws, size_t ws_size,
                              hipStream_t stream) {
  const float* hid      = (const float*)d_in[0];
  const float* w_ln1    = (const float*)d_in[1];
  const float* w_ln2    = (const float*)d_in[2];
  const float* W_qkvz   = (const float*)d_in[3];
  const float* W_ba     = (const float*)d_in[4];
  const float* conv_w   = (const float*)d_in[5];
  const float* dt_bias  = (const float*)d_in[6];
  const float* A_log    = (const float*)d_in[7];
  const float* gnw      = (const float*)d_in[8];
  const float* W_out    = (const float*)d_in[9];
  const float* W_router = (const float*)d_in[10];
  const float* W_gate   = (const float*)d_in[11];
  const float* W_up     = (const float*)d_in[12];
  const float* W_down   = (const float*)d_in[13];

  float* ws = (float*)d_ws;
  const size_t M1 = (size_t)1024 * 1024;
  float* x1    = ws;               // 2M (Sg0 during scan)
  float* qkvz  = x1 + 2 * M1;      // 6M
  float* conv  = qkvz + 6 * M1;    // 4M (Tc during scan; WgT/WuT after)
  float* qn    = conv + 4 * M1;    // 2M ┐ bc (4M contiguous)
  float* kn    = qn + 2 * M1;      // 2M ┘ (WdT after scan)
  float* core  = kn + 2 * M1;      // 2M
  float* Upre  = core + 2 * M1;    // 2M
  float* WpT   = Upre + 2 * M1;    // 2M
  float* Qdt   = WpT + 2 * M1;     // 2M
  float* Kdm   = Qdt + 2 * M1;     // 2M (act after scan)
  float* BqT   = Kdm + 2 * M1;     // 1M
  float* Sg1   = BqT + M1;         // 2M (heads 4-7 S_start)
  float* dec   = Sg1 + 2 * M1;     // 256
  float* ba    = dec + 256;        // 32768
  float* gb    = ba + 32768;       // 16384
  float* betab = gb + 16384;       // 16384
  float* rinfo = betab + 16384;    // 8192
  int*   ints  = (int*)(rinfo + 8192);
  int* cnt     = ints;             // 8
  int* cnt2    = ints + 8;         // 8
  int* offs    = ints + 16;        // 8
  int* pairTok = ints + 32;        // 4096
  int* tokPos  = ints + 4128;      // 4096
  u16* x1b     = (u16*)(ints + 8224);  // 2M u16

  float* Tc  = conv;
  float* bcb = qn;                 // spans qn+kn
  float* Sg0 = x1;
  u16* WgT = (u16*)conv;           // after chunkS3
  u16* WuT = (u16*)(conv + 2 * M1);
  u16* WdT = (u16*)kn;
  u16* act = (u16*)Kdm;
  float* eo = Upre;                // spans Upre+WpT

  float* outF = (float*)d_out;
  const size_t N1 = (size_t)S * HID;

  hipMemsetAsync(cnt, 0, 16 * sizeof(int), stream);

  k_rms<<<S, 256, 0, stream>>>(hid, w_ln1, x1, x1b);
  k_sgemm3<<<dim3(QKVZ_N / 128, S / 64), 256, 0, stream>>>(x1, W_qkvz, nullptr, qkvz,
                                                           S, QKVZ_N, HID);
  k_ba<<<S, 256, 0, stream>>>(x1, W_ba, ba);
  k_bg<<<(S * HV + 255) / 256, 256, 0, stream>>>(ba, dt_bias, A_log, gb, betab);
  k_conv<<<(S * CONV_DIM) / 256, 256, 0, stream>>>(qkvz, conv_w, conv);
  k_prep<<<S, 512, 0, stream>>>(conv, qn, kn);
  k_chunkA<<<HV * NC, 256, 0, stream>>>(qn, kn, conv, gb, betab,
                                        Upre, WpT, Qdt, Kdm, BqT, dec);
  k_chunkT<<<dim3(4, 32, 8), 256, 0, stream>>>(WpT, Kdm, Upre, dec, Tc, bcb);
  k_chunkS3<<<128, 256, 0, stream>>>(Tc, bcb, Sg0, Sg1);
  k_transp<<<dim3(16, 32, 8), 256, 0, stream>>>(W_gate, WgT, 1024, 512);
  k_transp<<<dim3(16, 32, 8), 256, 0, stream>>>(W_up, WuT, 1024, 512);
  k_transp<<<dim3(32, 16, 8), 256, 0, stream>>>(W_down, WdT, 512, 1024);
  k_chunkO<<<dim3(8, 32, 8), 256, 0, stream>>>(Upre, WpT, Qdt, BqT, Sg0, Sg1, core);
  k_gatenorm<<<dim3(S, 2), 256, 0, stream>>>(core, qkvz, gnw, core);
  k_sgemm3<<<dim3(HID / 128, S / 64), 256, 0, stream>>>(core, W_out, hid, outF,
                                                        S, HID, VAL_DIM);
  k_rms<<<S, 256, 0, stream>>>(outF, w_ln2, x1, x1b);
  k_router<<<S, 256, 0, stream>>>(x1, W_router, rinfo, cnt, outF + N1);
  k_offsets<<<1, 64, 0, stream>>>(cnt, offs, cnt2);
  k_scatter<<<(S + 255) / 256, 256, 0, stream>>>(rinfo, offs, cnt2, pairTok, tokPos);
  k_moe1m<<<dim3(4, 32, 8), 256, 0, stream>>>(x1b, WgT, WuT, offs, cnt, pairTok, act);
  k_moe2m<<<dim3(8, 32, 8), 256, 0, stream>>>(act, WdT, offs, cnt, eo);
  k_finish<<<S, 256, 0, stream>>>(eo, tokPos, rinfo, outF);
}